// Round 1
// baseline (978.707 us; speedup 1.0000x reference)
//
#include <hip/hip_runtime.h>
#include <hip/hip_bf16.h>
#include <cstdint>

// ---------------------------------------------------------------------------
// GraphRLAgent: 2-layer GAT (heads=2 then 1) + global mean pool + 2 heads.
// N=50000 nodes, E=800000 edges (+N self loops), F_IN=128, HID=128, G=64, A=32.
// Strategy round 1 (correctness + sane structure):
//   - CSR-by-dst built on device once per call (degree/scan/scatter).
//   - fp32 row-tiled GEMM (32 rows/block, x staged in LDS, broadcast reads).
//   - per-(node,head) wave aggregation: atomic-free softmax + msg gather.
// ---------------------------------------------------------------------------

#define LANES 64

__device__ __forceinline__ float wave_sum(float v) {
#pragma unroll
    for (int off = 32; off >= 1; off >>= 1) v += __shfl_xor(v, off, 64);
    return v;
}

// ------------------------- CSR construction -------------------------------

__global__ void zero_int_kernel(int* __restrict__ p, int n) {
    int i = blockIdx.x * blockDim.x + threadIdx.x;
    if (i < n) p[i] = 0;
}

__global__ void degree_kernel(const int* __restrict__ ei, int* __restrict__ deg,
                              int E, int N) {
    int i = blockIdx.x * blockDim.x + threadIdx.x;
    if (i >= E + N) return;
    int dst = (i < E) ? ei[E + i] : (i - E);
    atomicAdd(&deg[dst], 1);
}

__global__ __launch_bounds__(1024) void scan_kernel(const int* __restrict__ deg,
                                                    int* __restrict__ rowptr,
                                                    int* __restrict__ cursor, int N) {
    __shared__ int buf[1024];
    __shared__ int carry;
    int tid = threadIdx.x;
    if (tid == 0) carry = 0;
    __syncthreads();
    for (int base = 0; base < N; base += 1024) {
        int i = base + tid;
        int v = (i < N) ? deg[i] : 0;
        buf[tid] = v;
        __syncthreads();
#pragma unroll
        for (int off = 1; off < 1024; off <<= 1) {
            int t = (tid >= off) ? buf[tid - off] : 0;
            __syncthreads();
            buf[tid] += t;
            __syncthreads();
        }
        int excl = buf[tid] - v;
        int c = carry;
        if (i < N) { rowptr[i] = c + excl; cursor[i] = c + excl; }
        __syncthreads();
        if (tid == 0) carry += buf[1023];
        __syncthreads();
    }
    if (tid == 0) rowptr[N] = carry;
}

__global__ void scatter_kernel(const int* __restrict__ ei, int* __restrict__ cursor,
                               int* __restrict__ csr_src, int E, int N) {
    int i = blockIdx.x * blockDim.x + threadIdx.x;
    if (i >= E + N) return;
    int src, dst;
    if (i < E) { src = ei[i]; dst = ei[E + i]; }
    else       { src = dst = i - E; }
    int pos = atomicAdd(&cursor[dst], 1);
    csr_src[pos] = src;
}

// ------------------------- fp32 GEMM (row-tiled) --------------------------
// H[n, j] = sum_k X[n,k] * W[k,j].  Block: FOUT threads, NODES rows staged in LDS.

template <int FIN, int FOUT, int NODES>
__global__ __launch_bounds__(FOUT) void gemm_rows(const float* __restrict__ X,
                                                  const float* __restrict__ W,
                                                  float* __restrict__ Hout, int N) {
    __shared__ float xs[NODES * FIN];
    const int n0 = blockIdx.x * NODES;
    const int tid = threadIdx.x;
    for (int idx = tid; idx < NODES * FIN; idx += FOUT) {
        int m = idx / FIN;
        xs[idx] = (n0 + m < N) ? X[(size_t)n0 * FIN + idx] : 0.f;
    }
    __syncthreads();
    float acc[NODES];
#pragma unroll
    for (int m = 0; m < NODES; ++m) acc[m] = 0.f;
    for (int k = 0; k < FIN; ++k) {
        float w = W[k * FOUT + tid];
#pragma unroll
        for (int m = 0; m < NODES; ++m) acc[m] += xs[m * FIN + k] * w;
    }
#pragma unroll
    for (int m = 0; m < NODES; ++m) {
        int n = n0 + m;
        if (n < N) Hout[(size_t)n * FOUT + tid] = acc[m];
    }
}

// ------------------------- attention coefficients -------------------------
// es[n,h] = dot(Hpre[n,h,:], a_src[h,:]);  ed analogous.  One wave per (n,h).

__global__ void attn_coef(const float* __restrict__ Hpre, const float* __restrict__ a_src,
                          const float* __restrict__ a_dst, float* __restrict__ es,
                          float* __restrict__ ed, int N, int H) {
    int wid = (blockIdx.x * blockDim.x + threadIdx.x) >> 6;
    int lane = threadIdx.x & 63;
    if (wid >= N * H) return;
    int h = wid % H;
    const float* hp = Hpre + (size_t)wid * 128;  // wid = n*H + h, rows are [H*128]
    const float* as = a_src + h * 128;
    const float* ad = a_dst + h * 128;
    float v0 = hp[lane], v1 = hp[lane + 64];
    float ps = v0 * as[lane] + v1 * as[lane + 64];
    float pd = v0 * ad[lane] + v1 * ad[lane + 64];
    ps = wave_sum(ps);
    pd = wave_sum(pd);
    if (lane == 0) { es[wid] = ps; ed[wid] = pd; }
}

// ------------------------- GAT aggregation (atomic-free) ------------------
// One wave per (node, head). Softmax over incoming edges (no max-shift: alpha
// is shift-invariant and |e| is O(10) here), then alpha-weighted gather-sum
// of Hpre rows. Epilogue: + bias, ELU.

template <int H>
__global__ void gat_aggregate(const float* __restrict__ Hpre, const float* __restrict__ es,
                              const float* __restrict__ ed, const int* __restrict__ rowptr,
                              const int* __restrict__ csr_src, const float* __restrict__ bias,
                              float* __restrict__ out, int N) {
    int wid = (blockIdx.x * blockDim.x + threadIdx.x) >> 6;
    int lane = threadIdx.x & 63;
    if (wid >= N * H) return;
    int n = wid / H, h = wid % H;
    int rs = rowptr[n], re = rowptr[n + 1];
    float edn = ed[wid];

    // pass 1: z = sum over incoming edges of exp(leaky_relu(e_src+e_dst))
    float z = 0.f;
    for (int i = rs + lane; i < re; i += 64) {
        int s = csr_src[i];
        float e = es[s * H + h] + edn;
        e = (e > 0.f) ? e : 0.2f * e;
        z += __expf(e);
    }
    z = wave_sum(z);
    float rz = 1.f / (z + 1e-16f);

    // pass 2: acc = sum alpha * Hpre[src, h, :]; lanes cover 128 ch as float2
    float ax = 0.f, ay = 0.f;
    for (int i = rs; i < re; ++i) {
        int s = csr_src[i];
        float e = es[s * H + h] + edn;
        e = (e > 0.f) ? e : 0.2f * e;
        float alpha = __expf(e) * rz;
        const float2 v = *(const float2*)(Hpre + ((size_t)s * H + h) * 128 + lane * 2);
        ax += alpha * v.x;
        ay += alpha * v.y;
    }
    int j = h * 128 + lane * 2;
    float o0 = ax + bias[j];
    float o1 = ay + bias[j + 1];
    o0 = (o0 > 0.f) ? o0 : __expf(o0) - 1.f;
    o1 = (o1 > 0.f) ? o1 : __expf(o1) - 1.f;
    float2 o = make_float2(o0, o1);
    *(float2*)(out + ((size_t)n * H + h) * 128 + lane * 2) = o;
}

// ------------------------- global mean pool -------------------------------
// batch is sorted; one block per graph, binary-search the node range.

__global__ void pool_kernel(const float* __restrict__ h2, const int* __restrict__ batch,
                            float* __restrict__ xpool, int N) {
    int g = blockIdx.x;
    __shared__ int sh_start, sh_end;
    if (threadIdx.x == 0) {
        int lo = 0, hi = N;
        while (lo < hi) { int mid = (lo + hi) >> 1; if (batch[mid] < g) lo = mid + 1; else hi = mid; }
        sh_start = lo;
        lo = 0; hi = N;
        while (lo < hi) { int mid = (lo + hi) >> 1; if (batch[mid] < g + 1) lo = mid + 1; else hi = mid; }
        sh_end = lo;
    }
    __syncthreads();
    int start = sh_start, end = sh_end;
    int c = threadIdx.x & 127, part = threadIdx.x >> 7;
    float acc = 0.f;
    for (int i = start + part; i < end; i += 2) acc += h2[(size_t)i * 128 + c];
    __shared__ float red[256];
    red[threadIdx.x] = acc;
    __syncthreads();
    if (threadIdx.x < 128) {
        float s = red[threadIdx.x] + red[threadIdx.x + 128];
        int cnt = end - start;
        xpool[g * 128 + threadIdx.x] = s / fmaxf((float)cnt, 1.f);
    }
}

// ------------------------- policy / value heads ---------------------------

__global__ void head_kernel(const float* __restrict__ xpool, const float* __restrict__ Wp,
                            const float* __restrict__ bp, const float* __restrict__ Wv,
                            const float* __restrict__ bv, float* __restrict__ out) {
    int g = blockIdx.x, t = threadIdx.x;  // 64 threads
    __shared__ float p[128];
    p[t] = xpool[g * 128 + t];
    p[t + 64] = xpool[g * 128 + t + 64];
    __syncthreads();
    if (t < 32) {
        float acc = bp[t];
        for (int k = 0; k < 128; ++k) acc += p[k] * Wp[k * 32 + t];
        out[g * 32 + t] = acc;
    } else if (t == 32) {
        float acc = bv[0];
        for (int k = 0; k < 128; ++k) acc += p[k] * Wv[k];
        out[64 * 32 + g] = acc;
    }
}

// ---------------------------------------------------------------------------

extern "C" void kernel_launch(void* const* d_in, const int* in_sizes, int n_in,
                              void* d_out, int out_size, void* d_ws, size_t ws_size,
                              hipStream_t stream) {
    const float* x      = (const float*)d_in[0];
    const int*   ei     = (const int*)d_in[1];
    const int*   batch  = (const int*)d_in[2];
    const float* W1     = (const float*)d_in[3];
    const float* a_src1 = (const float*)d_in[4];
    const float* a_dst1 = (const float*)d_in[5];
    const float* b1     = (const float*)d_in[6];
    const float* W2     = (const float*)d_in[7];
    const float* a_src2 = (const float*)d_in[8];
    const float* a_dst2 = (const float*)d_in[9];
    const float* b2     = (const float*)d_in[10];
    const float* Wp     = (const float*)d_in[11];
    const float* bp     = (const float*)d_in[12];
    const float* Wv     = (const float*)d_in[13];
    const float* bv     = (const float*)d_in[14];

    const int N  = in_sizes[0] / 128;
    const int E  = in_sizes[1] / 2;
    const int ET = E + N;

    char* ws = (char*)d_ws;
    size_t off = 0;
    auto alloc = [&](size_t bytes) -> void* {
        void* p = ws + off;
        off = (off + bytes + 255) & ~(size_t)255;
        return p;
    };
    float* h1pre  = (float*)alloc((size_t)N * 256 * 4);  // later reused: h2pre + h2
    float* h1     = (float*)alloc((size_t)N * 256 * 4);
    float* es1    = (float*)alloc((size_t)N * 2 * 4);
    float* ed1    = (float*)alloc((size_t)N * 2 * 4);
    float* es2    = (float*)alloc((size_t)N * 4);
    float* ed2    = (float*)alloc((size_t)N * 4);
    int*   deg    = (int*)alloc((size_t)N * 4);
    int*   rowptr = (int*)alloc((size_t)(N + 1) * 4);
    int*   cursor = (int*)alloc((size_t)N * 4);
    int*   csrsrc = (int*)alloc((size_t)ET * 4);
    float* xpool  = (float*)alloc((size_t)64 * 128 * 4);
    float* h2pre  = h1pre;               // reuse: h1pre dead after layer-1 agg
    float* h2     = h1pre + (size_t)N * 128;

    // --- CSR build ---
    zero_int_kernel<<<(N + 255) / 256, 256, 0, stream>>>(deg, N);
    degree_kernel<<<(ET + 255) / 256, 256, 0, stream>>>(ei, deg, E, N);
    scan_kernel<<<1, 1024, 0, stream>>>(deg, rowptr, cursor, N);
    scatter_kernel<<<(ET + 255) / 256, 256, 0, stream>>>(ei, cursor, csrsrc, E, N);

    // --- layer 1: heads=2 ---
    gemm_rows<128, 256, 32><<<(N + 31) / 32, 256, 0, stream>>>(x, W1, h1pre, N);
    attn_coef<<<(N * 2 + 3) / 4, 256, 0, stream>>>(h1pre, a_src1, a_dst1, es1, ed1, N, 2);
    gat_aggregate<2><<<(N * 2 + 3) / 4, 256, 0, stream>>>(h1pre, es1, ed1, rowptr, csrsrc,
                                                          b1, h1, N);
    // --- layer 2: heads=1 ---
    gemm_rows<256, 128, 32><<<(N + 31) / 32, 128, 0, stream>>>(h1, W2, h2pre, N);
    attn_coef<<<(N + 3) / 4, 256, 0, stream>>>(h2pre, a_src2, a_dst2, es2, ed2, N, 1);
    gat_aggregate<1><<<(N + 3) / 4, 256, 0, stream>>>(h2pre, es2, ed2, rowptr, csrsrc,
                                                      b2, h2, N);
    // --- pool + heads ---
    pool_kernel<<<64, 256, 0, stream>>>(h2, batch, xpool, N);
    head_kernel<<<64, 64, 0, stream>>>(xpool, Wp, bp, Wv, bv, (float*)d_out);
}

// Round 2
// 780.152 us; speedup vs baseline: 1.2545x; 1.2545x over previous
//
#include <hip/hip_runtime.h>
#include <hip/hip_bf16.h>
#include <cstdint>

// ---------------------------------------------------------------------------
// GraphRLAgent: 2-layer GAT (heads=2 then 1) + global mean pool + 2 heads.
// Round 2: latency-optimized aggregation (precomputed edge weights, float4
// gathers, 2x unroll, multi-row in flight), hierarchical scan, faster GEMM
// inner loop (b128 LDS reads reused over 4 k-steps).
// ---------------------------------------------------------------------------

__device__ __forceinline__ float wave_sum(float v) {
#pragma unroll
    for (int off = 32; off >= 1; off >>= 1) v += __shfl_xor(v, off, 64);
    return v;
}

// ------------------------- CSR construction -------------------------------

__global__ void zero_int_kernel(int* __restrict__ p, int n) {
    int i = blockIdx.x * blockDim.x + threadIdx.x;
    if (i < n) p[i] = 0;
}

__global__ void degree_kernel(const int* __restrict__ ei, int* __restrict__ deg,
                              int E, int N) {
    int i = blockIdx.x * blockDim.x + threadIdx.x;
    if (i >= E + N) return;
    int dst = (i < E) ? ei[E + i] : (i - E);
    atomicAdd(&deg[dst], 1);
}

// tile scan: each block scans 1024 elements in-place (deg -> exclusive prefix),
// writes tile total. 256 threads, 4 elements/thread.
__global__ __launch_bounds__(256) void scan_tiles(int* __restrict__ deg,
                                                  int* __restrict__ tsum, int N) {
    __shared__ int buf[256];
    const int t = threadIdx.x;
    const int base = blockIdx.x * 1024 + t * 4;
    int v[4]; int s = 0;
#pragma unroll
    for (int k = 0; k < 4; ++k) { v[k] = (base + k < N) ? deg[base + k] : 0; s += v[k]; }
    buf[t] = s;
    __syncthreads();
#pragma unroll
    for (int off = 1; off < 256; off <<= 1) {
        int x = (t >= off) ? buf[t - off] : 0;
        __syncthreads();
        buf[t] += x;
        __syncthreads();
    }
    int run = buf[t] - s;  // exclusive prefix of this thread's chunk
#pragma unroll
    for (int k = 0; k < 4; ++k) {
        if (base + k < N) deg[base + k] = run;
        run += v[k];
    }
    if (t == 255) tsum[blockIdx.x] = buf[255];
}

// single-wave exclusive scan of tile sums (T <= 64); writes total to rowptrN.
__global__ void scan_sums(int* __restrict__ tsum, int* __restrict__ toff,
                          int* __restrict__ rowptrN, int T) {
    int t = threadIdx.x;  // 64 threads
    int v = (t < T) ? tsum[t] : 0;
    int orig = v;
#pragma unroll
    for (int off = 1; off < 64; off <<= 1) {
        int x = __shfl_up(v, off, 64);
        if (t >= off) v += x;
    }
    if (t < T) toff[t] = v - orig;
    if (t == 63) *rowptrN = v;
}

__global__ void scan_add(const int* __restrict__ partial, const int* __restrict__ toff,
                         int* __restrict__ rowptr, int* __restrict__ cursor, int N) {
    int i = blockIdx.x * blockDim.x + threadIdx.x;
    if (i < N) {
        int r = partial[i] + toff[i >> 10];
        rowptr[i] = r;
        cursor[i] = r;
    }
}

__global__ void scatter_kernel(const int* __restrict__ ei, int* __restrict__ cursor,
                               int* __restrict__ csr_src, int* __restrict__ csr_dst,
                               int E, int N) {
    int i = blockIdx.x * blockDim.x + threadIdx.x;
    if (i >= E + N) return;
    int src, dst;
    if (i < E) { src = ei[i]; dst = ei[E + i]; }
    else       { src = dst = i - E; }
    int pos = atomicAdd(&cursor[dst], 1);
    csr_src[pos] = src;
    csr_dst[pos] = dst;
}

// ------------------------- fp32 GEMM (row-tiled) --------------------------

template <int FIN, int FOUT, int NODES>
__global__ __launch_bounds__(FOUT) void gemm_rows(const float* __restrict__ X,
                                                  const float* __restrict__ W,
                                                  float* __restrict__ Hout, int N) {
    __shared__ float xs[NODES * FIN];
    const int n0 = blockIdx.x * NODES;
    const int tid = threadIdx.x;
    for (int idx = tid; idx < NODES * FIN; idx += FOUT) {
        int m = idx / FIN;
        xs[idx] = (n0 + m < N) ? X[(size_t)n0 * FIN + idx] : 0.f;
    }
    __syncthreads();
    float acc[NODES];
#pragma unroll
    for (int m = 0; m < NODES; ++m) acc[m] = 0.f;
    for (int k = 0; k < FIN; k += 4) {
        float w0 = W[(k + 0) * FOUT + tid];
        float w1 = W[(k + 1) * FOUT + tid];
        float w2 = W[(k + 2) * FOUT + tid];
        float w3 = W[(k + 3) * FOUT + tid];
#pragma unroll
        for (int m = 0; m < NODES; ++m) {
            float4 xv = *(const float4*)(xs + m * FIN + k);
            acc[m] += xv.x * w0 + xv.y * w1 + xv.z * w2 + xv.w * w3;
        }
    }
#pragma unroll
    for (int m = 0; m < NODES; ++m) {
        int n = n0 + m;
        if (n < N) Hout[(size_t)n * FOUT + tid] = acc[m];
    }
}

// ------------------------- attention coefficients -------------------------

__global__ void attn_coef(const float* __restrict__ Hpre, const float* __restrict__ a_src,
                          const float* __restrict__ a_dst, float* __restrict__ es,
                          float* __restrict__ ed, int N, int H) {
    int wid = (blockIdx.x * blockDim.x + threadIdx.x) >> 6;
    int lane = threadIdx.x & 63;
    if (wid >= N * H) return;
    int h = wid % H;
    const float* hp = Hpre + (size_t)wid * 128;
    const float* as = a_src + h * 128;
    const float* ad = a_dst + h * 128;
    float v0 = hp[lane], v1 = hp[lane + 64];
    float ps = v0 * as[lane] + v1 * as[lane + 64];
    float pd = v0 * ad[lane] + v1 * ad[lane + 64];
    ps = wave_sum(ps);
    pd = wave_sum(pd);
    if (lane == 0) { es[wid] = ps; ed[wid] = pd; }
}

// ------------------------- per-edge weights (CSR order) -------------------
// w[i*H+h] = exp(leaky_relu(es[src,h] + ed[dst,h]))  — unnormalized; the
// aggregate divides by the per-node sum, so the softmax max-shift cancels.

template <int H>
__global__ void edge_w_kernel(const float* __restrict__ es, const float* __restrict__ ed,
                              const int* __restrict__ csr_src, const int* __restrict__ csr_dst,
                              float* __restrict__ w, int ET) {
    int i = blockIdx.x * blockDim.x + threadIdx.x;
    if (i >= ET) return;
    int s = csr_src[i], n = csr_dst[i];
#pragma unroll
    for (int h = 0; h < H; ++h) {
        float e = es[s * H + h] + ed[n * H + h];
        e = (e > 0.f) ? e : 0.2f * e;
        w[i * H + h] = __expf(e);
    }
}

// ------------------------- GAT aggregation, H=2 ---------------------------
// One wave per node. Half-wave = head; both halves gather the SAME source row
// (1024 B fully coalesced per edge). 2x unroll -> 2048 B in flight.

__global__ void gat_agg_h2(const float* __restrict__ Hpre, const float* __restrict__ w,
                           const int* __restrict__ rowptr, const int* __restrict__ csr_src,
                           const float* __restrict__ bias, float* __restrict__ out, int N) {
    int wid = (blockIdx.x * blockDim.x + threadIdx.x) >> 6;
    int lane = threadIdx.x & 63;
    if (wid >= N) return;
    const int rs = rowptr[wid], re = rowptr[wid + 1];
    const int h = lane >> 5, c = lane & 31;

    float z = 0.f;
    for (int i = rs + c; i < re; i += 32) z += w[i * 2 + h];
#pragma unroll
    for (int off = 16; off >= 1; off >>= 1) z += __shfl_xor(z, off, 64);  // half-wave sum
    const float rz = 1.f / (z + 1e-16f);

    float4 a0 = {0.f, 0.f, 0.f, 0.f}, a1 = {0.f, 0.f, 0.f, 0.f};
    int i = rs;
    for (; i + 2 <= re; i += 2) {
        int s0 = csr_src[i], s1 = csr_src[i + 1];
        float w0 = w[i * 2 + h], w1 = w[i * 2 + 2 + h];
        float4 v0 = *((const float4*)(Hpre + ((size_t)s0 * 2 + h) * 128) + c);
        float4 v1 = *((const float4*)(Hpre + ((size_t)s1 * 2 + h) * 128) + c);
        a0.x += w0 * v0.x; a0.y += w0 * v0.y; a0.z += w0 * v0.z; a0.w += w0 * v0.w;
        a1.x += w1 * v1.x; a1.y += w1 * v1.y; a1.z += w1 * v1.z; a1.w += w1 * v1.w;
    }
    if (i < re) {
        int s0 = csr_src[i];
        float w0 = w[i * 2 + h];
        float4 v0 = *((const float4*)(Hpre + ((size_t)s0 * 2 + h) * 128) + c);
        a0.x += w0 * v0.x; a0.y += w0 * v0.y; a0.z += w0 * v0.z; a0.w += w0 * v0.w;
    }
    float4 bv = ((const float4*)bias)[lane];  // lane = h*32+c, bias is 256 floats
    float ox = (a0.x + a1.x) * rz + bv.x;
    float oy = (a0.y + a1.y) * rz + bv.y;
    float oz = (a0.z + a1.z) * rz + bv.z;
    float ow = (a0.w + a1.w) * rz + bv.w;
    ox = (ox > 0.f) ? ox : __expf(ox) - 1.f;
    oy = (oy > 0.f) ? oy : __expf(oy) - 1.f;
    oz = (oz > 0.f) ? oz : __expf(oz) - 1.f;
    ow = (ow > 0.f) ? ow : __expf(ow) - 1.f;
    *((float4*)(out + (size_t)wid * 256) + lane) = make_float4(ox, oy, oz, ow);
}

// ------------------------- GAT aggregation, H=1 ---------------------------
// One wave per node. Half-wave per edge (2 edges in flight), 2x unroll -> 4.

__global__ void gat_agg_h1(const float* __restrict__ Hpre, const float* __restrict__ w,
                           const int* __restrict__ rowptr, const int* __restrict__ csr_src,
                           const float* __restrict__ bias, float* __restrict__ out, int N) {
    int wid = (blockIdx.x * blockDim.x + threadIdx.x) >> 6;
    int lane = threadIdx.x & 63;
    if (wid >= N) return;
    const int rs = rowptr[wid], re = rowptr[wid + 1];
    const int half = lane >> 5, c = lane & 31;

    float z = 0.f;
    for (int i = rs + lane; i < re; i += 64) z += w[i];
    z = wave_sum(z);
    const float rz = 1.f / (z + 1e-16f);

    float4 a0 = {0.f, 0.f, 0.f, 0.f}, a1 = {0.f, 0.f, 0.f, 0.f};
    int i = rs + half;
    for (; i < re - 2; i += 4) {
        int s0 = csr_src[i], s1 = csr_src[i + 2];
        float w0 = w[i], w1 = w[i + 2];
        float4 v0 = ((const float4*)(Hpre + (size_t)s0 * 128))[c];
        float4 v1 = ((const float4*)(Hpre + (size_t)s1 * 128))[c];
        a0.x += w0 * v0.x; a0.y += w0 * v0.y; a0.z += w0 * v0.z; a0.w += w0 * v0.w;
        a1.x += w1 * v1.x; a1.y += w1 * v1.y; a1.z += w1 * v1.z; a1.w += w1 * v1.w;
    }
    if (i < re) {
        int s0 = csr_src[i];
        float w0 = w[i];
        float4 v0 = ((const float4*)(Hpre + (size_t)s0 * 128))[c];
        a0.x += w0 * v0.x; a0.y += w0 * v0.y; a0.z += w0 * v0.z; a0.w += w0 * v0.w;
    }
    float ox = a0.x + a1.x, oy = a0.y + a1.y, oz = a0.z + a1.z, ow = a0.w + a1.w;
    ox += __shfl_xor(ox, 32, 64);
    oy += __shfl_xor(oy, 32, 64);
    oz += __shfl_xor(oz, 32, 64);
    ow += __shfl_xor(ow, 32, 64);
    if (lane < 32) {
        float4 bv = ((const float4*)bias)[c];
        ox = ox * rz + bv.x; oy = oy * rz + bv.y; oz = oz * rz + bv.z; ow = ow * rz + bv.w;
        ox = (ox > 0.f) ? ox : __expf(ox) - 1.f;
        oy = (oy > 0.f) ? oy : __expf(oy) - 1.f;
        oz = (oz > 0.f) ? oz : __expf(oz) - 1.f;
        ow = (ow > 0.f) ? ow : __expf(ow) - 1.f;
        *((float4*)(out + (size_t)wid * 128) + c) = make_float4(ox, oy, oz, ow);
    }
}

// ------------------------- global mean pool -------------------------------

__global__ void pool_kernel(const float* __restrict__ h2, const int* __restrict__ batch,
                            float* __restrict__ xpool, int N) {
    int g = blockIdx.x;
    __shared__ int sh_start, sh_end;
    if (threadIdx.x == 0) {
        int lo = 0, hi = N;
        while (lo < hi) { int mid = (lo + hi) >> 1; if (batch[mid] < g) lo = mid + 1; else hi = mid; }
        sh_start = lo;
        lo = 0; hi = N;
        while (lo < hi) { int mid = (lo + hi) >> 1; if (batch[mid] < g + 1) lo = mid + 1; else hi = mid; }
        sh_end = lo;
    }
    __syncthreads();
    int start = sh_start, end = sh_end;
    int c = threadIdx.x & 127, part = threadIdx.x >> 7;
    float acc = 0.f;
    for (int i = start + part; i < end; i += 2) acc += h2[(size_t)i * 128 + c];
    __shared__ float red[256];
    red[threadIdx.x] = acc;
    __syncthreads();
    if (threadIdx.x < 128) {
        float s = red[threadIdx.x] + red[threadIdx.x + 128];
        int cnt = end - start;
        xpool[g * 128 + threadIdx.x] = s / fmaxf((float)cnt, 1.f);
    }
}

// ------------------------- policy / value heads ---------------------------

__global__ void head_kernel(const float* __restrict__ xpool, const float* __restrict__ Wp,
                            const float* __restrict__ bp, const float* __restrict__ Wv,
                            const float* __restrict__ bv, float* __restrict__ out) {
    int g = blockIdx.x, t = threadIdx.x;  // 64 threads
    __shared__ float p[128];
    p[t] = xpool[g * 128 + t];
    p[t + 64] = xpool[g * 128 + t + 64];
    __syncthreads();
    if (t < 32) {
        float acc = bp[t];
        for (int k = 0; k < 128; ++k) acc += p[k] * Wp[k * 32 + t];
        out[g * 32 + t] = acc;
    } else if (t == 32) {
        float acc = bv[0];
        for (int k = 0; k < 128; ++k) acc += p[k] * Wv[k];
        out[64 * 32 + g] = acc;
    }
}

// ---------------------------------------------------------------------------

extern "C" void kernel_launch(void* const* d_in, const int* in_sizes, int n_in,
                              void* d_out, int out_size, void* d_ws, size_t ws_size,
                              hipStream_t stream) {
    const float* x      = (const float*)d_in[0];
    const int*   ei     = (const int*)d_in[1];
    const int*   batch  = (const int*)d_in[2];
    const float* W1     = (const float*)d_in[3];
    const float* a_src1 = (const float*)d_in[4];
    const float* a_dst1 = (const float*)d_in[5];
    const float* b1     = (const float*)d_in[6];
    const float* W2     = (const float*)d_in[7];
    const float* a_src2 = (const float*)d_in[8];
    const float* a_dst2 = (const float*)d_in[9];
    const float* b2     = (const float*)d_in[10];
    const float* Wp     = (const float*)d_in[11];
    const float* bp     = (const float*)d_in[12];
    const float* Wv     = (const float*)d_in[13];
    const float* bv     = (const float*)d_in[14];

    const int N  = in_sizes[0] / 128;
    const int E  = in_sizes[1] / 2;
    const int ET = E + N;
    const int TILES = (N + 1023) / 1024;

    char* ws = (char*)d_ws;
    size_t off = 0;
    auto alloc = [&](size_t bytes) -> void* {
        void* p = ws + off;
        off = (off + bytes + 255) & ~(size_t)255;
        return p;
    };
    float* h1pre  = (float*)alloc((size_t)N * 256 * 4);  // reused as h2pre + h2
    float* h1     = (float*)alloc((size_t)N * 256 * 4);
    float* wbuf   = (float*)alloc((size_t)ET * 2 * 4);   // edge weights (2 heads max)
    float* es1    = (float*)alloc((size_t)N * 2 * 4);
    float* ed1    = (float*)alloc((size_t)N * 2 * 4);
    float* es2    = (float*)alloc((size_t)N * 4);
    float* ed2    = (float*)alloc((size_t)N * 4);
    int*   deg    = (int*)alloc((size_t)N * 4);          // becomes tile-local prefix
    int*   rowptr = (int*)alloc((size_t)(N + 1) * 4);
    int*   cursor = (int*)alloc((size_t)N * 4);
    int*   csrsrc = (int*)alloc((size_t)ET * 4);
    int*   csrdst = (int*)alloc((size_t)ET * 4);
    int*   tsum   = (int*)alloc(64 * 4);
    int*   toff   = (int*)alloc(64 * 4);
    float* xpool  = (float*)alloc((size_t)64 * 128 * 4);
    float* h2pre  = h1pre;               // h1pre dead after layer-1 agg
    float* h2     = h1pre + (size_t)N * 128;

    // --- CSR build ---
    zero_int_kernel<<<(N + 255) / 256, 256, 0, stream>>>(deg, N);
    degree_kernel<<<(ET + 255) / 256, 256, 0, stream>>>(ei, deg, E, N);
    scan_tiles<<<TILES, 256, 0, stream>>>(deg, tsum, N);
    scan_sums<<<1, 64, 0, stream>>>(tsum, toff, rowptr + N, TILES);
    scan_add<<<(N + 255) / 256, 256, 0, stream>>>(deg, toff, rowptr, cursor, N);
    scatter_kernel<<<(ET + 255) / 256, 256, 0, stream>>>(ei, cursor, csrsrc, csrdst, E, N);

    // --- layer 1: heads=2 ---
    gemm_rows<128, 256, 32><<<(N + 31) / 32, 256, 0, stream>>>(x, W1, h1pre, N);
    attn_coef<<<(N * 2 + 3) / 4, 256, 0, stream>>>(h1pre, a_src1, a_dst1, es1, ed1, N, 2);
    edge_w_kernel<2><<<(ET + 255) / 256, 256, 0, stream>>>(es1, ed1, csrsrc, csrdst, wbuf, ET);
    gat_agg_h2<<<(N + 3) / 4, 256, 0, stream>>>(h1pre, wbuf, rowptr, csrsrc, b1, h1, N);

    // --- layer 2: heads=1 ---
    gemm_rows<256, 128, 32><<<(N + 31) / 32, 128, 0, stream>>>(h1, W2, h2pre, N);
    attn_coef<<<(N + 3) / 4, 256, 0, stream>>>(h2pre, a_src2, a_dst2, es2, ed2, N, 1);
    edge_w_kernel<1><<<(ET + 255) / 256, 256, 0, stream>>>(es2, ed2, csrsrc, csrdst, wbuf, ET);
    gat_agg_h1<<<(N + 3) / 4, 256, 0, stream>>>(h2pre, wbuf, rowptr, csrsrc, b2, h2, N);

    // --- pool + heads ---
    pool_kernel<<<64, 256, 0, stream>>>(h2, batch, xpool, N);
    head_kernel<<<64, 64, 0, stream>>>(xpool, Wp, bp, Wv, bv, (float*)d_out);
}

// Round 3
// 592.503 us; speedup vs baseline: 1.6518x; 1.3167x over previous
//
#include <hip/hip_runtime.h>
#include <hip/hip_bf16.h>
#include <cstdint>

// ---------------------------------------------------------------------------
// GraphRLAgent: 2-layer GAT (heads=2 then 1) + global mean pool + 2 heads.
// Round 3: bf16 MFMA GEMMs (LDS-free: B frags in regs from L2, A frags as
// per-lane contiguous dwordx4). Aggregation/CSR/pool unchanged from round 2.
// ---------------------------------------------------------------------------

typedef __attribute__((ext_vector_type(8))) short bf16x8;
typedef __attribute__((ext_vector_type(4))) float f32x4;

__device__ __forceinline__ float wave_sum(float v) {
#pragma unroll
    for (int off = 32; off >= 1; off >>= 1) v += __shfl_xor(v, off, 64);
    return v;
}

__device__ __forceinline__ unsigned short f2bf(float f) {
    union { float f; uint32_t u; } c; c.f = f;
    uint32_t u = c.u;
    return (unsigned short)((u + 0x7fffu + ((u >> 16) & 1u)) >> 16);
}

// ------------------------- CSR construction -------------------------------

__global__ void zero_int_kernel(int* __restrict__ p, int n) {
    int i = blockIdx.x * blockDim.x + threadIdx.x;
    if (i < n) p[i] = 0;
}

__global__ void degree_kernel(const int* __restrict__ ei, int* __restrict__ deg,
                              int E, int N) {
    int i = blockIdx.x * blockDim.x + threadIdx.x;
    if (i >= E + N) return;
    int dst = (i < E) ? ei[E + i] : (i - E);
    atomicAdd(&deg[dst], 1);
}

__global__ __launch_bounds__(256) void scan_tiles(int* __restrict__ deg,
                                                  int* __restrict__ tsum, int N) {
    __shared__ int buf[256];
    const int t = threadIdx.x;
    const int base = blockIdx.x * 1024 + t * 4;
    int v[4]; int s = 0;
#pragma unroll
    for (int k = 0; k < 4; ++k) { v[k] = (base + k < N) ? deg[base + k] : 0; s += v[k]; }
    buf[t] = s;
    __syncthreads();
#pragma unroll
    for (int off = 1; off < 256; off <<= 1) {
        int x = (t >= off) ? buf[t - off] : 0;
        __syncthreads();
        buf[t] += x;
        __syncthreads();
    }
    int run = buf[t] - s;
#pragma unroll
    for (int k = 0; k < 4; ++k) {
        if (base + k < N) deg[base + k] = run;
        run += v[k];
    }
    if (t == 255) tsum[blockIdx.x] = buf[255];
}

__global__ void scan_sums(int* __restrict__ tsum, int* __restrict__ toff,
                          int* __restrict__ rowptrN, int T) {
    int t = threadIdx.x;  // 64 threads
    int v = (t < T) ? tsum[t] : 0;
    int orig = v;
#pragma unroll
    for (int off = 1; off < 64; off <<= 1) {
        int x = __shfl_up(v, off, 64);
        if (t >= off) v += x;
    }
    if (t < T) toff[t] = v - orig;
    if (t == 63) *rowptrN = v;
}

__global__ void scan_add(const int* __restrict__ partial, const int* __restrict__ toff,
                         int* __restrict__ rowptr, int* __restrict__ cursor, int N) {
    int i = blockIdx.x * blockDim.x + threadIdx.x;
    if (i < N) {
        int r = partial[i] + toff[i >> 10];
        rowptr[i] = r;
        cursor[i] = r;
    }
}

__global__ void scatter_kernel(const int* __restrict__ ei, int* __restrict__ cursor,
                               int* __restrict__ csr_src, int* __restrict__ csr_dst,
                               int E, int N) {
    int i = blockIdx.x * blockDim.x + threadIdx.x;
    if (i >= E + N) return;
    int src, dst;
    if (i < E) { src = ei[i]; dst = ei[E + i]; }
    else       { src = dst = i - E; }
    int pos = atomicAdd(&cursor[dst], 1);
    csr_src[pos] = src;
    csr_dst[pos] = dst;
}

// ------------------------- fp32 -> bf16 cast ------------------------------
// dst[0:npad) with zero fill past n. npad % 4 == 0.

__global__ void cast_bf16_kernel(const float* __restrict__ src, unsigned short* __restrict__ dst,
                                 int n, int npad) {
    int i = (blockIdx.x * blockDim.x + threadIdx.x) * 4;
    if (i >= npad) return;
    float a, b, c, d;
    if (i + 3 < n) {
        float4 v = *(const float4*)(src + i);
        a = v.x; b = v.y; c = v.z; d = v.w;
    } else {
        a = (i + 0 < n) ? src[i + 0] : 0.f;
        b = (i + 1 < n) ? src[i + 1] : 0.f;
        c = (i + 2 < n) ? src[i + 2] : 0.f;
        d = (i + 3 < n) ? src[i + 3] : 0.f;
    }
    ushort4 o;
    o.x = f2bf(a); o.y = f2bf(b); o.z = f2bf(c); o.w = f2bf(d);
    *(ushort4*)(dst + i) = o;
}

// ------------------------- bf16 MFMA GEMM ---------------------------------
// C[N, FOUT] (fp32) = A[Npad, K] (bf16) x B[K, FOUT] (bf16).
// Block: 256 thr = 4 waves. Block tile: 64 rows x FOUT. Wave: 64 rows x FOUT/4.
// B frags held in registers (loaded once, L2-resident); A frags read as
// per-lane contiguous 16B from global (L1 catches 4x intra-block reuse).

template <int K, int FOUT>
__global__ __launch_bounds__(256) void gemm_mfma(const unsigned short* __restrict__ A,
                                                 const unsigned short* __restrict__ B,
                                                 float* __restrict__ C, int N) {
    constexpr int CPW = FOUT / 4;   // cols per wave
    constexpr int NCT = CPW / 16;   // col tiles per wave
    constexpr int KST = K / 32;     // k-steps
    const int tid = threadIdx.x;
    const int wave = tid >> 6, lane = tid & 63;
    const int quad = lane >> 4, lo = lane & 15;
    const int n0 = blockIdx.x * 64;
    const int c0 = wave * CPW;

    // B fragments: B[k = t*32 + quad*8 + j][n = c0 + c*16 + lo]
    bf16x8 bf[NCT][KST];
    {
        const unsigned short* Bp = B + c0 + lo;
#pragma unroll
        for (int c = 0; c < NCT; ++c)
#pragma unroll
            for (int t = 0; t < KST; ++t)
#pragma unroll
                for (int j = 0; j < 8; ++j)
                    bf[c][t][j] = (short)Bp[(t * 32 + quad * 8 + j) * FOUT + c * 16];
    }

    f32x4 acc[4][NCT];
#pragma unroll
    for (int r = 0; r < 4; ++r)
#pragma unroll
        for (int c = 0; c < NCT; ++c) acc[r][c] = (f32x4){0.f, 0.f, 0.f, 0.f};

#pragma unroll
    for (int r = 0; r < 4; ++r) {
        const unsigned short* Ar = A + (size_t)(n0 + r * 16 + lo) * K + quad * 8;
#pragma unroll
        for (int t = 0; t < KST; ++t) {
            bf16x8 af = *(const bf16x8*)(Ar + t * 32);
#pragma unroll
            for (int c = 0; c < NCT; ++c)
                acc[r][c] = __builtin_amdgcn_mfma_f32_16x16x32_bf16(af, bf[c][t], acc[r][c],
                                                                   0, 0, 0);
        }
    }

    // C/D layout: col = lane&15, row = quad*4 + j
#pragma unroll
    for (int r = 0; r < 4; ++r) {
        int row = n0 + r * 16 + quad * 4;
#pragma unroll
        for (int c = 0; c < NCT; ++c) {
            int col = c0 + c * 16 + lo;
#pragma unroll
            for (int j = 0; j < 4; ++j)
                if (row + j < N) C[(size_t)(row + j) * FOUT + col] = acc[r][c][j];
        }
    }
}

// ------------------------- attention coefficients -------------------------

__global__ void attn_coef(const float* __restrict__ Hpre, const float* __restrict__ a_src,
                          const float* __restrict__ a_dst, float* __restrict__ es,
                          float* __restrict__ ed, int N, int H) {
    int wid = (blockIdx.x * blockDim.x + threadIdx.x) >> 6;
    int lane = threadIdx.x & 63;
    if (wid >= N * H) return;
    int h = wid % H;
    const float* hp = Hpre + (size_t)wid * 128;
    const float* as = a_src + h * 128;
    const float* ad = a_dst + h * 128;
    float v0 = hp[lane], v1 = hp[lane + 64];
    float ps = v0 * as[lane] + v1 * as[lane + 64];
    float pd = v0 * ad[lane] + v1 * ad[lane + 64];
    ps = wave_sum(ps);
    pd = wave_sum(pd);
    if (lane == 0) { es[wid] = ps; ed[wid] = pd; }
}

// ------------------------- per-edge weights (CSR order) -------------------

template <int H>
__global__ void edge_w_kernel(const float* __restrict__ es, const float* __restrict__ ed,
                              const int* __restrict__ csr_src, const int* __restrict__ csr_dst,
                              float* __restrict__ w, int ET) {
    int i = blockIdx.x * blockDim.x + threadIdx.x;
    if (i >= ET) return;
    int s = csr_src[i], n = csr_dst[i];
#pragma unroll
    for (int h = 0; h < H; ++h) {
        float e = es[s * H + h] + ed[n * H + h];
        e = (e > 0.f) ? e : 0.2f * e;
        w[i * H + h] = __expf(e);
    }
}

// ------------------------- GAT aggregation, H=2 ---------------------------

__global__ void gat_agg_h2(const float* __restrict__ Hpre, const float* __restrict__ w,
                           const int* __restrict__ rowptr, const int* __restrict__ csr_src,
                           const float* __restrict__ bias, float* __restrict__ out, int N) {
    int wid = (blockIdx.x * blockDim.x + threadIdx.x) >> 6;
    int lane = threadIdx.x & 63;
    if (wid >= N) return;
    const int rs = rowptr[wid], re = rowptr[wid + 1];
    const int h = lane >> 5, c = lane & 31;

    float z = 0.f;
    for (int i = rs + c; i < re; i += 32) z += w[i * 2 + h];
#pragma unroll
    for (int off = 16; off >= 1; off >>= 1) z += __shfl_xor(z, off, 64);
    const float rz = 1.f / (z + 1e-16f);

    float4 a0 = {0.f, 0.f, 0.f, 0.f}, a1 = {0.f, 0.f, 0.f, 0.f};
    int i = rs;
    for (; i + 2 <= re; i += 2) {
        int s0 = csr_src[i], s1 = csr_src[i + 1];
        float w0 = w[i * 2 + h], w1 = w[i * 2 + 2 + h];
        float4 v0 = *((const float4*)(Hpre + ((size_t)s0 * 2 + h) * 128) + c);
        float4 v1 = *((const float4*)(Hpre + ((size_t)s1 * 2 + h) * 128) + c);
        a0.x += w0 * v0.x; a0.y += w0 * v0.y; a0.z += w0 * v0.z; a0.w += w0 * v0.w;
        a1.x += w1 * v1.x; a1.y += w1 * v1.y; a1.z += w1 * v1.z; a1.w += w1 * v1.w;
    }
    if (i < re) {
        int s0 = csr_src[i];
        float w0 = w[i * 2 + h];
        float4 v0 = *((const float4*)(Hpre + ((size_t)s0 * 2 + h) * 128) + c);
        a0.x += w0 * v0.x; a0.y += w0 * v0.y; a0.z += w0 * v0.z; a0.w += w0 * v0.w;
    }
    float4 bv = ((const float4*)bias)[lane];
    float ox = (a0.x + a1.x) * rz + bv.x;
    float oy = (a0.y + a1.y) * rz + bv.y;
    float oz = (a0.z + a1.z) * rz + bv.z;
    float ow = (a0.w + a1.w) * rz + bv.w;
    ox = (ox > 0.f) ? ox : __expf(ox) - 1.f;
    oy = (oy > 0.f) ? oy : __expf(oy) - 1.f;
    oz = (oz > 0.f) ? oz : __expf(oz) - 1.f;
    ow = (ow > 0.f) ? ow : __expf(ow) - 1.f;
    *((float4*)(out + (size_t)wid * 256) + lane) = make_float4(ox, oy, oz, ow);
}

// ------------------------- GAT aggregation, H=1 ---------------------------

__global__ void gat_agg_h1(const float* __restrict__ Hpre, const float* __restrict__ w,
                           const int* __restrict__ rowptr, const int* __restrict__ csr_src,
                           const float* __restrict__ bias, float* __restrict__ out, int N) {
    int wid = (blockIdx.x * blockDim.x + threadIdx.x) >> 6;
    int lane = threadIdx.x & 63;
    if (wid >= N) return;
    const int rs = rowptr[wid], re = rowptr[wid + 1];
    const int half = lane >> 5, c = lane & 31;

    float z = 0.f;
    for (int i = rs + lane; i < re; i += 64) z += w[i];
    z = wave_sum(z);
    const float rz = 1.f / (z + 1e-16f);

    float4 a0 = {0.f, 0.f, 0.f, 0.f}, a1 = {0.f, 0.f, 0.f, 0.f};
    int i = rs + half;
    for (; i < re - 2; i += 4) {
        int s0 = csr_src[i], s1 = csr_src[i + 2];
        float w0 = w[i], w1 = w[i + 2];
        float4 v0 = ((const float4*)(Hpre + (size_t)s0 * 128))[c];
        float4 v1 = ((const float4*)(Hpre + (size_t)s1 * 128))[c];
        a0.x += w0 * v0.x; a0.y += w0 * v0.y; a0.z += w0 * v0.z; a0.w += w0 * v0.w;
        a1.x += w1 * v1.x; a1.y += w1 * v1.y; a1.z += w1 * v1.z; a1.w += w1 * v1.w;
    }
    if (i < re) {
        int s0 = csr_src[i];
        float w0 = w[i];
        float4 v0 = ((const float4*)(Hpre + (size_t)s0 * 128))[c];
        a0.x += w0 * v0.x; a0.y += w0 * v0.y; a0.z += w0 * v0.z; a0.w += w0 * v0.w;
    }
    float ox = a0.x + a1.x, oy = a0.y + a1.y, oz = a0.z + a1.z, ow = a0.w + a1.w;
    ox += __shfl_xor(ox, 32, 64);
    oy += __shfl_xor(oy, 32, 64);
    oz += __shfl_xor(oz, 32, 64);
    ow += __shfl_xor(ow, 32, 64);
    if (lane < 32) {
        float4 bv = ((const float4*)bias)[c];
        ox = ox * rz + bv.x; oy = oy * rz + bv.y; oz = oz * rz + bv.z; ow = ow * rz + bv.w;
        ox = (ox > 0.f) ? ox : __expf(ox) - 1.f;
        oy = (oy > 0.f) ? oy : __expf(oy) - 1.f;
        oz = (oz > 0.f) ? oz : __expf(oz) - 1.f;
        ow = (ow > 0.f) ? ow : __expf(ow) - 1.f;
        *((float4*)(out + (size_t)wid * 128) + c) = make_float4(ox, oy, oz, ow);
    }
}

// ------------------------- global mean pool -------------------------------

__global__ void pool_kernel(const float* __restrict__ h2, const int* __restrict__ batch,
                            float* __restrict__ xpool, int N) {
    int g = blockIdx.x;
    __shared__ int sh_start, sh_end;
    if (threadIdx.x == 0) {
        int lo = 0, hi = N;
        while (lo < hi) { int mid = (lo + hi) >> 1; if (batch[mid] < g) lo = mid + 1; else hi = mid; }
        sh_start = lo;
        lo = 0; hi = N;
        while (lo < hi) { int mid = (lo + hi) >> 1; if (batch[mid] < g + 1) lo = mid + 1; else hi = mid; }
        sh_end = lo;
    }
    __syncthreads();
    int start = sh_start, end = sh_end;
    int c = threadIdx.x & 127, part = threadIdx.x >> 7;
    float acc = 0.f;
    for (int i = start + part; i < end; i += 2) acc += h2[(size_t)i * 128 + c];
    __shared__ float red[256];
    red[threadIdx.x] = acc;
    __syncthreads();
    if (threadIdx.x < 128) {
        float s = red[threadIdx.x] + red[threadIdx.x + 128];
        int cnt = end - start;
        xpool[g * 128 + threadIdx.x] = s / fmaxf((float)cnt, 1.f);
    }
}

// ------------------------- policy / value heads ---------------------------

__global__ void head_kernel(const float* __restrict__ xpool, const float* __restrict__ Wp,
                            const float* __restrict__ bp, const float* __restrict__ Wv,
                            const float* __restrict__ bv, float* __restrict__ out) {
    int g = blockIdx.x, t = threadIdx.x;  // 64 threads
    __shared__ float p[128];
    p[t] = xpool[g * 128 + t];
    p[t + 64] = xpool[g * 128 + t + 64];
    __syncthreads();
    if (t < 32) {
        float acc = bp[t];
        for (int k = 0; k < 128; ++k) acc += p[k] * Wp[k * 32 + t];
        out[g * 32 + t] = acc;
    } else if (t == 32) {
        float acc = bv[0];
        for (int k = 0; k < 128; ++k) acc += p[k] * Wv[k];
        out[64 * 32 + g] = acc;
    }
}

// ---------------------------------------------------------------------------

extern "C" void kernel_launch(void* const* d_in, const int* in_sizes, int n_in,
                              void* d_out, int out_size, void* d_ws, size_t ws_size,
                              hipStream_t stream) {
    const float* x      = (const float*)d_in[0];
    const int*   ei     = (const int*)d_in[1];
    const int*   batch  = (const int*)d_in[2];
    const float* W1     = (const float*)d_in[3];
    const float* a_src1 = (const float*)d_in[4];
    const float* a_dst1 = (const float*)d_in[5];
    const float* b1     = (const float*)d_in[6];
    const float* W2     = (const float*)d_in[7];
    const float* a_src2 = (const float*)d_in[8];
    const float* a_dst2 = (const float*)d_in[9];
    const float* b2     = (const float*)d_in[10];
    const float* Wp     = (const float*)d_in[11];
    const float* bp     = (const float*)d_in[12];
    const float* Wv     = (const float*)d_in[13];
    const float* bv     = (const float*)d_in[14];

    const int N  = in_sizes[0] / 128;
    const int E  = in_sizes[1] / 2;
    const int ET = E + N;
    const int TILES = (N + 1023) / 1024;
    const int NPAD = ((N + 63) / 64) * 64;
    const int NBLK = NPAD / 64;

    char* ws = (char*)d_ws;
    size_t off = 0;
    auto alloc = [&](size_t bytes) -> void* {
        void* p = ws + off;
        off = (off + bytes + 255) & ~(size_t)255;
        return p;
    };
    float* h1pre  = (float*)alloc((size_t)N * 256 * 4);   // reused as h2pre + h2
    float* h1     = (float*)alloc((size_t)N * 256 * 4);
    unsigned short* xbf  = (unsigned short*)alloc((size_t)NPAD * 128 * 2);
    unsigned short* h1bf = (unsigned short*)alloc((size_t)NPAD * 256 * 2);
    unsigned short* w1bf = (unsigned short*)alloc((size_t)128 * 256 * 2);
    unsigned short* w2bf = (unsigned short*)alloc((size_t)256 * 128 * 2);
    float* wbuf   = (float*)alloc((size_t)ET * 2 * 4);
    float* es1    = (float*)alloc((size_t)N * 2 * 4);
    float* ed1    = (float*)alloc((size_t)N * 2 * 4);
    float* es2    = (float*)alloc((size_t)N * 4);
    float* ed2    = (float*)alloc((size_t)N * 4);
    int*   deg    = (int*)alloc((size_t)N * 4);
    int*   rowptr = (int*)alloc((size_t)(N + 1) * 4);
    int*   cursor = (int*)alloc((size_t)N * 4);
    int*   csrsrc = (int*)alloc((size_t)ET * 4);
    int*   csrdst = (int*)alloc((size_t)ET * 4);
    int*   tsum   = (int*)alloc(64 * 4);
    int*   toff   = (int*)alloc(64 * 4);
    float* xpool  = (float*)alloc((size_t)64 * 128 * 4);
    float* h2pre  = h1pre;                 // h1pre dead after layer-1 agg
    float* h2     = h1pre + (size_t)N * 128;

    // --- CSR build ---
    zero_int_kernel<<<(N + 255) / 256, 256, 0, stream>>>(deg, N);
    degree_kernel<<<(ET + 255) / 256, 256, 0, stream>>>(ei, deg, E, N);
    scan_tiles<<<TILES, 256, 0, stream>>>(deg, tsum, N);
    scan_sums<<<1, 64, 0, stream>>>(tsum, toff, rowptr + N, TILES);
    scan_add<<<(N + 255) / 256, 256, 0, stream>>>(deg, toff, rowptr, cursor, N);
    scatter_kernel<<<(ET + 255) / 256, 256, 0, stream>>>(ei, cursor, csrsrc, csrdst, E, N);

    // --- casts for MFMA ---
    cast_bf16_kernel<<<(NPAD * 128 / 4 + 255) / 256, 256, 0, stream>>>(x, xbf, N * 128, NPAD * 128);
    cast_bf16_kernel<<<(128 * 256 / 4 + 255) / 256, 256, 0, stream>>>(W1, w1bf, 128 * 256, 128 * 256);
    cast_bf16_kernel<<<(256 * 128 / 4 + 255) / 256, 256, 0, stream>>>(W2, w2bf, 256 * 128, 256 * 128);

    // --- layer 1: heads=2 ---
    gemm_mfma<128, 256><<<NBLK, 256, 0, stream>>>(xbf, w1bf, h1pre, N);
    attn_coef<<<(N * 2 + 3) / 4, 256, 0, stream>>>(h1pre, a_src1, a_dst1, es1, ed1, N, 2);
    edge_w_kernel<2><<<(ET + 255) / 256, 256, 0, stream>>>(es1, ed1, csrsrc, csrdst, wbuf, ET);
    gat_agg_h2<<<(N + 3) / 4, 256, 0, stream>>>(h1pre, wbuf, rowptr, csrsrc, b1, h1, N);

    // --- layer 2: heads=1 ---
    cast_bf16_kernel<<<(NPAD * 256 / 4 + 255) / 256, 256, 0, stream>>>(h1, h1bf, N * 256, NPAD * 256);
    gemm_mfma<256, 128><<<NBLK, 256, 0, stream>>>(h1bf, w2bf, h2pre, N);
    attn_coef<<<(N + 3) / 4, 256, 0, stream>>>(h2pre, a_src2, a_dst2, es2, ed2, N, 1);
    edge_w_kernel<1><<<(ET + 255) / 256, 256, 0, stream>>>(es2, ed2, csrsrc, csrdst, wbuf, ET);
    gat_agg_h1<<<(N + 3) / 4, 256, 0, stream>>>(h2pre, wbuf, rowptr, csrsrc, b2, h2, N);

    // --- pool + heads ---
    pool_kernel<<<64, 256, 0, stream>>>(h2, batch, xpool, N);
    head_kernel<<<64, 64, 0, stream>>>(xpool, Wp, bp, Wv, bv, (float*)d_out);
}

// Round 4
// 501.146 us; speedup vs baseline: 1.9529x; 1.1823x over previous
//
#include <hip/hip_runtime.h>
#include <hip/hip_bf16.h>
#include <cstdint>

// ---------------------------------------------------------------------------
// GraphRLAgent: 2-layer GAT (heads=2 then 1) + global mean pool + 2 heads.
// Round 4: bf16 storage everywhere between GEMMs (fp32 accumulate).
//   - GEMM writes bf16 directly; gat_agg gathers bf16 rows (half the bytes);
//   - gat_agg_h2 epilogue emits bf16 = GEMM2's A operand (cast kernel gone);
//   - pool reads bf16. All reductions/accumulators remain fp32.
// ---------------------------------------------------------------------------

typedef __attribute__((ext_vector_type(8))) short bf16x8;
typedef __attribute__((ext_vector_type(4))) float f32x4;

__device__ __forceinline__ float wave_sum(float v) {
#pragma unroll
    for (int off = 32; off >= 1; off >>= 1) v += __shfl_xor(v, off, 64);
    return v;
}

__device__ __forceinline__ unsigned short f2bf(float f) {
    union { float f; uint32_t u; } c; c.f = f;
    uint32_t u = c.u;
    return (unsigned short)((u + 0x7fffu + ((u >> 16) & 1u)) >> 16);
}

__device__ __forceinline__ float bf2f(unsigned short u) {
    union { uint32_t u; float f; } c; c.u = ((uint32_t)u) << 16;
    return c.f;
}

// ------------------------- CSR construction -------------------------------

__global__ void zero_int_kernel(int* __restrict__ p, int n) {
    int i = blockIdx.x * blockDim.x + threadIdx.x;
    if (i < n) p[i] = 0;
}

__global__ void degree_kernel(const int* __restrict__ ei, int* __restrict__ deg,
                              int E, int N) {
    int i = blockIdx.x * blockDim.x + threadIdx.x;
    if (i >= E + N) return;
    int dst = (i < E) ? ei[E + i] : (i - E);
    atomicAdd(&deg[dst], 1);
}

__global__ __launch_bounds__(256) void scan_tiles(int* __restrict__ deg,
                                                  int* __restrict__ tsum, int N) {
    __shared__ int buf[256];
    const int t = threadIdx.x;
    const int base = blockIdx.x * 1024 + t * 4;
    int v[4]; int s = 0;
#pragma unroll
    for (int k = 0; k < 4; ++k) { v[k] = (base + k < N) ? deg[base + k] : 0; s += v[k]; }
    buf[t] = s;
    __syncthreads();
#pragma unroll
    for (int off = 1; off < 256; off <<= 1) {
        int x = (t >= off) ? buf[t - off] : 0;
        __syncthreads();
        buf[t] += x;
        __syncthreads();
    }
    int run = buf[t] - s;
#pragma unroll
    for (int k = 0; k < 4; ++k) {
        if (base + k < N) deg[base + k] = run;
        run += v[k];
    }
    if (t == 255) tsum[blockIdx.x] = buf[255];
}

__global__ void scan_sums(int* __restrict__ tsum, int* __restrict__ toff,
                          int* __restrict__ rowptrN, int T) {
    int t = threadIdx.x;  // 64 threads
    int v = (t < T) ? tsum[t] : 0;
    int orig = v;
#pragma unroll
    for (int off = 1; off < 64; off <<= 1) {
        int x = __shfl_up(v, off, 64);
        if (t >= off) v += x;
    }
    if (t < T) toff[t] = v - orig;
    if (t == 63) *rowptrN = v;
}

__global__ void scan_add(const int* __restrict__ partial, const int* __restrict__ toff,
                         int* __restrict__ rowptr, int* __restrict__ cursor, int N) {
    int i = blockIdx.x * blockDim.x + threadIdx.x;
    if (i < N) {
        int r = partial[i] + toff[i >> 10];
        rowptr[i] = r;
        cursor[i] = r;
    }
}

__global__ void scatter_kernel(const int* __restrict__ ei, int* __restrict__ cursor,
                               int* __restrict__ csr_src, int* __restrict__ csr_dst,
                               int E, int N) {
    int i = blockIdx.x * blockDim.x + threadIdx.x;
    if (i >= E + N) return;
    int src, dst;
    if (i < E) { src = ei[i]; dst = ei[E + i]; }
    else       { src = dst = i - E; }
    int pos = atomicAdd(&cursor[dst], 1);
    csr_src[pos] = src;
    csr_dst[pos] = dst;
}

// ------------------------- fp32 -> bf16 cast (zero-padded) ----------------

__global__ void cast_bf16_kernel(const float* __restrict__ src, unsigned short* __restrict__ dst,
                                 int n, int npad) {
    int i = (blockIdx.x * blockDim.x + threadIdx.x) * 4;
    if (i >= npad) return;
    float a, b, c, d;
    if (i + 3 < n) {
        float4 v = *(const float4*)(src + i);
        a = v.x; b = v.y; c = v.z; d = v.w;
    } else {
        a = (i + 0 < n) ? src[i + 0] : 0.f;
        b = (i + 1 < n) ? src[i + 1] : 0.f;
        c = (i + 2 < n) ? src[i + 2] : 0.f;
        d = (i + 3 < n) ? src[i + 3] : 0.f;
    }
    ushort4 o;
    o.x = f2bf(a); o.y = f2bf(b); o.z = f2bf(c); o.w = f2bf(d);
    *(ushort4*)(dst + i) = o;
}

// ------------------------- bf16 MFMA GEMM (bf16 out) ----------------------
// C[N, FOUT] (bf16) = A[Npad, K] (bf16) x B[K, FOUT] (bf16), fp32 accumulate.

template <int K, int FOUT>
__global__ __launch_bounds__(256) void gemm_mfma(const unsigned short* __restrict__ A,
                                                 const unsigned short* __restrict__ B,
                                                 unsigned short* __restrict__ C, int N) {
    constexpr int CPW = FOUT / 4;
    constexpr int NCT = CPW / 16;
    constexpr int KST = K / 32;
    const int tid = threadIdx.x;
    const int wave = tid >> 6, lane = tid & 63;
    const int quad = lane >> 4, lo = lane & 15;
    const int n0 = blockIdx.x * 64;
    const int c0 = wave * CPW;

    bf16x8 bf[NCT][KST];
    {
        const unsigned short* Bp = B + c0 + lo;
#pragma unroll
        for (int c = 0; c < NCT; ++c)
#pragma unroll
            for (int t = 0; t < KST; ++t)
#pragma unroll
                for (int j = 0; j < 8; ++j)
                    bf[c][t][j] = (short)Bp[(t * 32 + quad * 8 + j) * FOUT + c * 16];
    }

    f32x4 acc[4][NCT];
#pragma unroll
    for (int r = 0; r < 4; ++r)
#pragma unroll
        for (int c = 0; c < NCT; ++c) acc[r][c] = (f32x4){0.f, 0.f, 0.f, 0.f};

#pragma unroll
    for (int r = 0; r < 4; ++r) {
        const unsigned short* Ar = A + (size_t)(n0 + r * 16 + lo) * K + quad * 8;
#pragma unroll
        for (int t = 0; t < KST; ++t) {
            bf16x8 af = *(const bf16x8*)(Ar + t * 32);
#pragma unroll
            for (int c = 0; c < NCT; ++c)
                acc[r][c] = __builtin_amdgcn_mfma_f32_16x16x32_bf16(af, bf[c][t], acc[r][c],
                                                                   0, 0, 0);
        }
    }

    // C/D layout: col = lane&15, row = quad*4 + j
#pragma unroll
    for (int r = 0; r < 4; ++r) {
        int row = n0 + r * 16 + quad * 4;
#pragma unroll
        for (int c = 0; c < NCT; ++c) {
            int col = c0 + c * 16 + lo;
#pragma unroll
            for (int j = 0; j < 4; ++j)
                if (row + j < N) C[(size_t)(row + j) * FOUT + col] = f2bf(acc[r][c][j]);
        }
    }
}

// ------------------------- attention coefficients (bf16 in) ---------------

__global__ void attn_coef(const unsigned short* __restrict__ Hpre, const float* __restrict__ a_src,
                          const float* __restrict__ a_dst, float* __restrict__ es,
                          float* __restrict__ ed, int N, int H) {
    int wid = (blockIdx.x * blockDim.x + threadIdx.x) >> 6;
    int lane = threadIdx.x & 63;
    if (wid >= N * H) return;
    int h = wid % H;
    const unsigned short* hp = Hpre + (size_t)wid * 128;
    const float* as = a_src + h * 128;
    const float* ad = a_dst + h * 128;
    float v0 = bf2f(hp[lane]), v1 = bf2f(hp[lane + 64]);
    float ps = v0 * as[lane] + v1 * as[lane + 64];
    float pd = v0 * ad[lane] + v1 * ad[lane + 64];
    ps = wave_sum(ps);
    pd = wave_sum(pd);
    if (lane == 0) { es[wid] = ps; ed[wid] = pd; }
}

// ------------------------- per-edge weights (CSR order) -------------------

template <int H>
__global__ void edge_w_kernel(const float* __restrict__ es, const float* __restrict__ ed,
                              const int* __restrict__ csr_src, const int* __restrict__ csr_dst,
                              float* __restrict__ w, int ET) {
    int i = blockIdx.x * blockDim.x + threadIdx.x;
    if (i >= ET) return;
    int s = csr_src[i], n = csr_dst[i];
#pragma unroll
    for (int h = 0; h < H; ++h) {
        float e = es[s * H + h] + ed[n * H + h];
        e = (e > 0.f) ? e : 0.2f * e;
        w[i * H + h] = __expf(e);
    }
}

// ------------------------- GAT aggregation, H=2 (bf16 in/out) -------------
// One wave per node; lane covers channel lane*4 of the [2,128] row (512 B).

__global__ void gat_agg_h2(const unsigned short* __restrict__ Hpre, const float* __restrict__ w,
                           const int* __restrict__ rowptr, const int* __restrict__ csr_src,
                           const float* __restrict__ bias, unsigned short* __restrict__ out,
                           int N) {
    int wid = (blockIdx.x * blockDim.x + threadIdx.x) >> 6;
    int lane = threadIdx.x & 63;
    if (wid >= N) return;
    const int rs = rowptr[wid], re = rowptr[wid + 1];
    const int h = lane >> 5;

    float z = 0.f;
    for (int i = rs + (lane & 31); i < re; i += 32) z += w[i * 2 + h];
#pragma unroll
    for (int off = 16; off >= 1; off >>= 1) z += __shfl_xor(z, off, 64);
    const float rz = 1.f / (z + 1e-16f);

    float4 a0 = {0.f, 0.f, 0.f, 0.f}, a1 = {0.f, 0.f, 0.f, 0.f};
    int i = rs;
    for (; i + 2 <= re; i += 2) {
        int s0 = csr_src[i], s1 = csr_src[i + 1];
        float w0 = w[i * 2 + h], w1 = w[i * 2 + 2 + h];
        ushort4 u0 = *(const ushort4*)(Hpre + (size_t)s0 * 256 + lane * 4);
        ushort4 u1 = *(const ushort4*)(Hpre + (size_t)s1 * 256 + lane * 4);
        a0.x += w0 * bf2f(u0.x); a0.y += w0 * bf2f(u0.y);
        a0.z += w0 * bf2f(u0.z); a0.w += w0 * bf2f(u0.w);
        a1.x += w1 * bf2f(u1.x); a1.y += w1 * bf2f(u1.y);
        a1.z += w1 * bf2f(u1.z); a1.w += w1 * bf2f(u1.w);
    }
    if (i < re) {
        int s0 = csr_src[i];
        float w0 = w[i * 2 + h];
        ushort4 u0 = *(const ushort4*)(Hpre + (size_t)s0 * 256 + lane * 4);
        a0.x += w0 * bf2f(u0.x); a0.y += w0 * bf2f(u0.y);
        a0.z += w0 * bf2f(u0.z); a0.w += w0 * bf2f(u0.w);
    }
    float4 bv = ((const float4*)bias)[lane];
    float ox = (a0.x + a1.x) * rz + bv.x;
    float oy = (a0.y + a1.y) * rz + bv.y;
    float oz = (a0.z + a1.z) * rz + bv.z;
    float ow = (a0.w + a1.w) * rz + bv.w;
    ox = (ox > 0.f) ? ox : __expf(ox) - 1.f;
    oy = (oy > 0.f) ? oy : __expf(oy) - 1.f;
    oz = (oz > 0.f) ? oz : __expf(oz) - 1.f;
    ow = (ow > 0.f) ? ow : __expf(ow) - 1.f;
    ushort4 o;
    o.x = f2bf(ox); o.y = f2bf(oy); o.z = f2bf(oz); o.w = f2bf(ow);
    *(ushort4*)(out + (size_t)wid * 256 + lane * 4) = o;
}

// ------------------------- GAT aggregation, H=1 (bf16 in/out) -------------
// One wave per node; half-wave per edge (2 edges in flight), 2x unroll -> 4.

__global__ void gat_agg_h1(const unsigned short* __restrict__ Hpre, const float* __restrict__ w,
                           const int* __restrict__ rowptr, const int* __restrict__ csr_src,
                           const float* __restrict__ bias, unsigned short* __restrict__ out,
                           int N) {
    int wid = (blockIdx.x * blockDim.x + threadIdx.x) >> 6;
    int lane = threadIdx.x & 63;
    if (wid >= N) return;
    const int rs = rowptr[wid], re = rowptr[wid + 1];
    const int half = lane >> 5, c = lane & 31;

    float z = 0.f;
    for (int i = rs + lane; i < re; i += 64) z += w[i];
    z = wave_sum(z);
    const float rz = 1.f / (z + 1e-16f);

    float4 a0 = {0.f, 0.f, 0.f, 0.f}, a1 = {0.f, 0.f, 0.f, 0.f};
    int i = rs + half;
    for (; i < re - 2; i += 4) {
        int s0 = csr_src[i], s1 = csr_src[i + 2];
        float w0 = w[i], w1 = w[i + 2];
        ushort4 u0 = *(const ushort4*)(Hpre + (size_t)s0 * 128 + c * 4);
        ushort4 u1 = *(const ushort4*)(Hpre + (size_t)s1 * 128 + c * 4);
        a0.x += w0 * bf2f(u0.x); a0.y += w0 * bf2f(u0.y);
        a0.z += w0 * bf2f(u0.z); a0.w += w0 * bf2f(u0.w);
        a1.x += w1 * bf2f(u1.x); a1.y += w1 * bf2f(u1.y);
        a1.z += w1 * bf2f(u1.z); a1.w += w1 * bf2f(u1.w);
    }
    if (i < re) {
        int s0 = csr_src[i];
        float w0 = w[i];
        ushort4 u0 = *(const ushort4*)(Hpre + (size_t)s0 * 128 + c * 4);
        a0.x += w0 * bf2f(u0.x); a0.y += w0 * bf2f(u0.y);
        a0.z += w0 * bf2f(u0.z); a0.w += w0 * bf2f(u0.w);
    }
    float ox = a0.x + a1.x, oy = a0.y + a1.y, oz = a0.z + a1.z, ow = a0.w + a1.w;
    ox += __shfl_xor(ox, 32, 64);
    oy += __shfl_xor(oy, 32, 64);
    oz += __shfl_xor(oz, 32, 64);
    ow += __shfl_xor(ow, 32, 64);
    if (lane < 32) {
        float4 bv = ((const float4*)bias)[c];
        ox = ox * rz + bv.x; oy = oy * rz + bv.y; oz = oz * rz + bv.z; ow = ow * rz + bv.w;
        ox = (ox > 0.f) ? ox : __expf(ox) - 1.f;
        oy = (oy > 0.f) ? oy : __expf(oy) - 1.f;
        oz = (oz > 0.f) ? oz : __expf(oz) - 1.f;
        ow = (ow > 0.f) ? ow : __expf(ow) - 1.f;
        ushort4 o;
        o.x = f2bf(ox); o.y = f2bf(oy); o.z = f2bf(oz); o.w = f2bf(ow);
        *(ushort4*)(out + (size_t)wid * 128 + c * 4) = o;
    }
}

// ------------------------- global mean pool (bf16 in) ---------------------

__global__ void pool_kernel(const unsigned short* __restrict__ h2, const int* __restrict__ batch,
                            float* __restrict__ xpool, int N) {
    int g = blockIdx.x;
    __shared__ int sh_start, sh_end;
    if (threadIdx.x == 0) {
        int lo = 0, hi = N;
        while (lo < hi) { int mid = (lo + hi) >> 1; if (batch[mid] < g) lo = mid + 1; else hi = mid; }
        sh_start = lo;
        lo = 0; hi = N;
        while (lo < hi) { int mid = (lo + hi) >> 1; if (batch[mid] < g + 1) lo = mid + 1; else hi = mid; }
        sh_end = lo;
    }
    __syncthreads();
    int start = sh_start, end = sh_end;
    int c = threadIdx.x & 127, part = threadIdx.x >> 7;
    float acc = 0.f;
    for (int i = start + part; i < end; i += 2) acc += bf2f(h2[(size_t)i * 128 + c]);
    __shared__ float red[256];
    red[threadIdx.x] = acc;
    __syncthreads();
    if (threadIdx.x < 128) {
        float s = red[threadIdx.x] + red[threadIdx.x + 128];
        int cnt = end - start;
        xpool[g * 128 + threadIdx.x] = s / fmaxf((float)cnt, 1.f);
    }
}

// ------------------------- policy / value heads ---------------------------

__global__ void head_kernel(const float* __restrict__ xpool, const float* __restrict__ Wp,
                            const float* __restrict__ bp, const float* __restrict__ Wv,
                            const float* __restrict__ bv, float* __restrict__ out) {
    int g = blockIdx.x, t = threadIdx.x;  // 64 threads
    __shared__ float p[128];
    p[t] = xpool[g * 128 + t];
    p[t + 64] = xpool[g * 128 + t + 64];
    __syncthreads();
    if (t < 32) {
        float acc = bp[t];
        for (int k = 0; k < 128; ++k) acc += p[k] * Wp[k * 32 + t];
        out[g * 32 + t] = acc;
    } else if (t == 32) {
        float acc = bv[0];
        for (int k = 0; k < 128; ++k) acc += p[k] * Wv[k];
        out[64 * 32 + g] = acc;
    }
}

// ---------------------------------------------------------------------------

extern "C" void kernel_launch(void* const* d_in, const int* in_sizes, int n_in,
                              void* d_out, int out_size, void* d_ws, size_t ws_size,
                              hipStream_t stream) {
    const float* x      = (const float*)d_in[0];
    const int*   ei     = (const int*)d_in[1];
    const int*   batch  = (const int*)d_in[2];
    const float* W1     = (const float*)d_in[3];
    const float* a_src1 = (const float*)d_in[4];
    const float* a_dst1 = (const float*)d_in[5];
    const float* b1     = (const float*)d_in[6];
    const float* W2     = (const float*)d_in[7];
    const float* a_src2 = (const float*)d_in[8];
    const float* a_dst2 = (const float*)d_in[9];
    const float* b2     = (const float*)d_in[10];
    const float* Wp     = (const float*)d_in[11];
    const float* bp     = (const float*)d_in[12];
    const float* Wv     = (const float*)d_in[13];
    const float* bv     = (const float*)d_in[14];

    const int N  = in_sizes[0] / 128;
    const int E  = in_sizes[1] / 2;
    const int ET = E + N;
    const int TILES = (N + 1023) / 1024;
    const int NPAD = ((N + 63) / 64) * 64;
    const int NBLK = NPAD / 64;

    char* ws = (char*)d_ws;
    size_t off = 0;
    auto alloc = [&](size_t bytes) -> void* {
        void* p = ws + off;
        off = (off + bytes + 255) & ~(size_t)255;
        return p;
    };
    unsigned short* h1pre = (unsigned short*)alloc((size_t)NPAD * 256 * 2);  // reused as h2pre
    unsigned short* h1bf  = (unsigned short*)alloc((size_t)NPAD * 256 * 2);
    unsigned short* xbf   = (unsigned short*)alloc((size_t)NPAD * 128 * 2);
    unsigned short* h2bf  = (unsigned short*)alloc((size_t)N * 128 * 2);
    unsigned short* w1bf  = (unsigned short*)alloc((size_t)128 * 256 * 2);
    unsigned short* w2bf  = (unsigned short*)alloc((size_t)256 * 128 * 2);
    float* wbuf   = (float*)alloc((size_t)ET * 2 * 4);
    float* es1    = (float*)alloc((size_t)N * 2 * 4);
    float* ed1    = (float*)alloc((size_t)N * 2 * 4);
    float* es2    = (float*)alloc((size_t)N * 4);
    float* ed2    = (float*)alloc((size_t)N * 4);
    int*   deg    = (int*)alloc((size_t)N * 4);
    int*   rowptr = (int*)alloc((size_t)(N + 1) * 4);
    int*   cursor = (int*)alloc((size_t)N * 4);
    int*   csrsrc = (int*)alloc((size_t)ET * 4);
    int*   csrdst = (int*)alloc((size_t)ET * 4);
    int*   tsum   = (int*)alloc(64 * 4);
    int*   toff   = (int*)alloc(64 * 4);
    float* xpool  = (float*)alloc((size_t)64 * 128 * 4);
    unsigned short* h2pre = h1pre;  // h1pre dead after layer-1 agg

    // --- CSR build ---
    zero_int_kernel<<<(N + 255) / 256, 256, 0, stream>>>(deg, N);
    degree_kernel<<<(ET + 255) / 256, 256, 0, stream>>>(ei, deg, E, N);
    scan_tiles<<<TILES, 256, 0, stream>>>(deg, tsum, N);
    scan_sums<<<1, 64, 0, stream>>>(tsum, toff, rowptr + N, TILES);
    scan_add<<<(N + 255) / 256, 256, 0, stream>>>(deg, toff, rowptr, cursor, N);
    scatter_kernel<<<(ET + 255) / 256, 256, 0, stream>>>(ei, cursor, csrsrc, csrdst, E, N);

    // --- casts ---
    cast_bf16_kernel<<<(NPAD * 128 / 4 + 255) / 256, 256, 0, stream>>>(x, xbf, N * 128, NPAD * 128);
    cast_bf16_kernel<<<(128 * 256 / 4 + 255) / 256, 256, 0, stream>>>(W1, w1bf, 128 * 256, 128 * 256);
    cast_bf16_kernel<<<(256 * 128 / 4 + 255) / 256, 256, 0, stream>>>(W2, w2bf, 256 * 128, 256 * 128);

    // --- layer 1: heads=2 ---
    gemm_mfma<128, 256><<<NBLK, 256, 0, stream>>>(xbf, w1bf, h1pre, N);
    attn_coef<<<(N * 2 + 3) / 4, 256, 0, stream>>>(h1pre, a_src1, a_dst1, es1, ed1, N, 2);
    edge_w_kernel<2><<<(ET + 255) / 256, 256, 0, stream>>>(es1, ed1, csrsrc, csrdst, wbuf, ET);
    gat_agg_h2<<<(N + 3) / 4, 256, 0, stream>>>(h1pre, wbuf, rowptr, csrsrc, b1, h1bf, N);

    // --- layer 2: heads=1 ---
    gemm_mfma<256, 128><<<NBLK, 256, 0, stream>>>(h1bf, w2bf, h2pre, N);
    attn_coef<<<(N + 3) / 4, 256, 0, stream>>>(h2pre, a_src2, a_dst2, es2, ed2, N, 1);
    edge_w_kernel<1><<<(ET + 255) / 256, 256, 0, stream>>>(es2, ed2, csrsrc, csrdst, wbuf, ET);
    gat_agg_h1<<<(N + 3) / 4, 256, 0, stream>>>(h2pre, wbuf, rowptr, csrsrc, b2, h2bf, N);

    // --- pool + heads ---
    pool_kernel<<<64, 256, 0, stream>>>(h2bf, batch, xpool, N);
    head_kernel<<<64, 64, 0, stream>>>(xpool, Wp, bp, Wv, bv, (float*)d_out);
}

// Round 5
// 426.801 us; speedup vs baseline: 2.2931x; 1.1742x over previous
//
#include <hip/hip_runtime.h>
#include <hip/hip_bf16.h>
#include <cstdint>

// ---------------------------------------------------------------------------
// GraphRLAgent: 2-layer GAT (heads=2 then 1) + global mean pool + 2 heads.
// Round 5: chunk-parallel pool (196 blocks + atomic flush-on-graph-change)
// replacing the 64-block latency-bound pool (112 us -> ~8 us predicted).
// ---------------------------------------------------------------------------

typedef __attribute__((ext_vector_type(8))) short bf16x8;
typedef __attribute__((ext_vector_type(4))) float f32x4;

__device__ __forceinline__ float wave_sum(float v) {
#pragma unroll
    for (int off = 32; off >= 1; off >>= 1) v += __shfl_xor(v, off, 64);
    return v;
}

__device__ __forceinline__ unsigned short f2bf(float f) {
    union { float f; uint32_t u; } c; c.f = f;
    uint32_t u = c.u;
    return (unsigned short)((u + 0x7fffu + ((u >> 16) & 1u)) >> 16);
}

__device__ __forceinline__ float bf2f(unsigned short u) {
    union { uint32_t u; float f; } c; c.u = ((uint32_t)u) << 16;
    return c.f;
}

// ------------------------- CSR construction -------------------------------

__global__ void zero_int_kernel(int* __restrict__ p, int n) {
    int i = blockIdx.x * blockDim.x + threadIdx.x;
    if (i < n) p[i] = 0;
}

__global__ void degree_kernel(const int* __restrict__ ei, int* __restrict__ deg,
                              int E, int N) {
    int i = blockIdx.x * blockDim.x + threadIdx.x;
    if (i >= E + N) return;
    int dst = (i < E) ? ei[E + i] : (i - E);
    atomicAdd(&deg[dst], 1);
}

__global__ __launch_bounds__(256) void scan_tiles(int* __restrict__ deg,
                                                  int* __restrict__ tsum, int N) {
    __shared__ int buf[256];
    const int t = threadIdx.x;
    const int base = blockIdx.x * 1024 + t * 4;
    int v[4]; int s = 0;
#pragma unroll
    for (int k = 0; k < 4; ++k) { v[k] = (base + k < N) ? deg[base + k] : 0; s += v[k]; }
    buf[t] = s;
    __syncthreads();
#pragma unroll
    for (int off = 1; off < 256; off <<= 1) {
        int x = (t >= off) ? buf[t - off] : 0;
        __syncthreads();
        buf[t] += x;
        __syncthreads();
    }
    int run = buf[t] - s;
#pragma unroll
    for (int k = 0; k < 4; ++k) {
        if (base + k < N) deg[base + k] = run;
        run += v[k];
    }
    if (t == 255) tsum[blockIdx.x] = buf[255];
}

__global__ void scan_sums(int* __restrict__ tsum, int* __restrict__ toff,
                          int* __restrict__ rowptrN, int T) {
    int t = threadIdx.x;  // 64 threads
    int v = (t < T) ? tsum[t] : 0;
    int orig = v;
#pragma unroll
    for (int off = 1; off < 64; off <<= 1) {
        int x = __shfl_up(v, off, 64);
        if (t >= off) v += x;
    }
    if (t < T) toff[t] = v - orig;
    if (t == 63) *rowptrN = v;
}

__global__ void scan_add(const int* __restrict__ partial, const int* __restrict__ toff,
                         int* __restrict__ rowptr, int* __restrict__ cursor, int N) {
    int i = blockIdx.x * blockDim.x + threadIdx.x;
    if (i < N) {
        int r = partial[i] + toff[i >> 10];
        rowptr[i] = r;
        cursor[i] = r;
    }
}

__global__ void scatter_kernel(const int* __restrict__ ei, int* __restrict__ cursor,
                               int* __restrict__ csr_src, int* __restrict__ csr_dst,
                               int E, int N) {
    int i = blockIdx.x * blockDim.x + threadIdx.x;
    if (i >= E + N) return;
    int src, dst;
    if (i < E) { src = ei[i]; dst = ei[E + i]; }
    else       { src = dst = i - E; }
    int pos = atomicAdd(&cursor[dst], 1);
    csr_src[pos] = src;
    csr_dst[pos] = dst;
}

// ------------------------- fp32 -> bf16 cast (zero-padded) ----------------

__global__ void cast_bf16_kernel(const float* __restrict__ src, unsigned short* __restrict__ dst,
                                 int n, int npad) {
    int i = (blockIdx.x * blockDim.x + threadIdx.x) * 4;
    if (i >= npad) return;
    float a, b, c, d;
    if (i + 3 < n) {
        float4 v = *(const float4*)(src + i);
        a = v.x; b = v.y; c = v.z; d = v.w;
    } else {
        a = (i + 0 < n) ? src[i + 0] : 0.f;
        b = (i + 1 < n) ? src[i + 1] : 0.f;
        c = (i + 2 < n) ? src[i + 2] : 0.f;
        d = (i + 3 < n) ? src[i + 3] : 0.f;
    }
    ushort4 o;
    o.x = f2bf(a); o.y = f2bf(b); o.z = f2bf(c); o.w = f2bf(d);
    *(ushort4*)(dst + i) = o;
}

// ------------------------- bf16 MFMA GEMM (bf16 out) ----------------------

template <int K, int FOUT>
__global__ __launch_bounds__(256) void gemm_mfma(const unsigned short* __restrict__ A,
                                                 const unsigned short* __restrict__ B,
                                                 unsigned short* __restrict__ C, int N) {
    constexpr int CPW = FOUT / 4;
    constexpr int NCT = CPW / 16;
    constexpr int KST = K / 32;
    const int tid = threadIdx.x;
    const int wave = tid >> 6, lane = tid & 63;
    const int quad = lane >> 4, lo = lane & 15;
    const int n0 = blockIdx.x * 64;
    const int c0 = wave * CPW;

    bf16x8 bf[NCT][KST];
    {
        const unsigned short* Bp = B + c0 + lo;
#pragma unroll
        for (int c = 0; c < NCT; ++c)
#pragma unroll
            for (int t = 0; t < KST; ++t)
#pragma unroll
                for (int j = 0; j < 8; ++j)
                    bf[c][t][j] = (short)Bp[(t * 32 + quad * 8 + j) * FOUT + c * 16];
    }

    f32x4 acc[4][NCT];
#pragma unroll
    for (int r = 0; r < 4; ++r)
#pragma unroll
        for (int c = 0; c < NCT; ++c) acc[r][c] = (f32x4){0.f, 0.f, 0.f, 0.f};

#pragma unroll
    for (int r = 0; r < 4; ++r) {
        const unsigned short* Ar = A + (size_t)(n0 + r * 16 + lo) * K + quad * 8;
#pragma unroll
        for (int t = 0; t < KST; ++t) {
            bf16x8 af = *(const bf16x8*)(Ar + t * 32);
#pragma unroll
            for (int c = 0; c < NCT; ++c)
                acc[r][c] = __builtin_amdgcn_mfma_f32_16x16x32_bf16(af, bf[c][t], acc[r][c],
                                                                   0, 0, 0);
        }
    }

    // C/D layout: col = lane&15, row = quad*4 + j
#pragma unroll
    for (int r = 0; r < 4; ++r) {
        int row = n0 + r * 16 + quad * 4;
#pragma unroll
        for (int c = 0; c < NCT; ++c) {
            int col = c0 + c * 16 + lo;
#pragma unroll
            for (int j = 0; j < 4; ++j)
                if (row + j < N) C[(size_t)(row + j) * FOUT + col] = f2bf(acc[r][c][j]);
        }
    }
}

// ------------------------- attention coefficients (bf16 in) ---------------

__global__ void attn_coef(const unsigned short* __restrict__ Hpre, const float* __restrict__ a_src,
                          const float* __restrict__ a_dst, float* __restrict__ es,
                          float* __restrict__ ed, int N, int H) {
    int wid = (blockIdx.x * blockDim.x + threadIdx.x) >> 6;
    int lane = threadIdx.x & 63;
    if (wid >= N * H) return;
    int h = wid % H;
    const unsigned short* hp = Hpre + (size_t)wid * 128;
    const float* as = a_src + h * 128;
    const float* ad = a_dst + h * 128;
    float v0 = bf2f(hp[lane]), v1 = bf2f(hp[lane + 64]);
    float ps = v0 * as[lane] + v1 * as[lane + 64];
    float pd = v0 * ad[lane] + v1 * ad[lane + 64];
    ps = wave_sum(ps);
    pd = wave_sum(pd);
    if (lane == 0) { es[wid] = ps; ed[wid] = pd; }
}

// ------------------------- per-edge weights (CSR order) -------------------

template <int H>
__global__ void edge_w_kernel(const float* __restrict__ es, const float* __restrict__ ed,
                              const int* __restrict__ csr_src, const int* __restrict__ csr_dst,
                              float* __restrict__ w, int ET) {
    int i = blockIdx.x * blockDim.x + threadIdx.x;
    if (i >= ET) return;
    int s = csr_src[i], n = csr_dst[i];
#pragma unroll
    for (int h = 0; h < H; ++h) {
        float e = es[s * H + h] + ed[n * H + h];
        e = (e > 0.f) ? e : 0.2f * e;
        w[i * H + h] = __expf(e);
    }
}

// ------------------------- GAT aggregation, H=2 (bf16 in/out) -------------

__global__ void gat_agg_h2(const unsigned short* __restrict__ Hpre, const float* __restrict__ w,
                           const int* __restrict__ rowptr, const int* __restrict__ csr_src,
                           const float* __restrict__ bias, unsigned short* __restrict__ out,
                           int N) {
    int wid = (blockIdx.x * blockDim.x + threadIdx.x) >> 6;
    int lane = threadIdx.x & 63;
    if (wid >= N) return;
    const int rs = rowptr[wid], re = rowptr[wid + 1];
    const int h = lane >> 5;

    float z = 0.f;
    for (int i = rs + (lane & 31); i < re; i += 32) z += w[i * 2 + h];
#pragma unroll
    for (int off = 16; off >= 1; off >>= 1) z += __shfl_xor(z, off, 64);
    const float rz = 1.f / (z + 1e-16f);

    float4 a0 = {0.f, 0.f, 0.f, 0.f}, a1 = {0.f, 0.f, 0.f, 0.f};
    int i = rs;
    for (; i + 2 <= re; i += 2) {
        int s0 = csr_src[i], s1 = csr_src[i + 1];
        float w0 = w[i * 2 + h], w1 = w[i * 2 + 2 + h];
        ushort4 u0 = *(const ushort4*)(Hpre + (size_t)s0 * 256 + lane * 4);
        ushort4 u1 = *(const ushort4*)(Hpre + (size_t)s1 * 256 + lane * 4);
        a0.x += w0 * bf2f(u0.x); a0.y += w0 * bf2f(u0.y);
        a0.z += w0 * bf2f(u0.z); a0.w += w0 * bf2f(u0.w);
        a1.x += w1 * bf2f(u1.x); a1.y += w1 * bf2f(u1.y);
        a1.z += w1 * bf2f(u1.z); a1.w += w1 * bf2f(u1.w);
    }
    if (i < re) {
        int s0 = csr_src[i];
        float w0 = w[i * 2 + h];
        ushort4 u0 = *(const ushort4*)(Hpre + (size_t)s0 * 256 + lane * 4);
        a0.x += w0 * bf2f(u0.x); a0.y += w0 * bf2f(u0.y);
        a0.z += w0 * bf2f(u0.z); a0.w += w0 * bf2f(u0.w);
    }
    float4 bv = ((const float4*)bias)[lane];
    float ox = (a0.x + a1.x) * rz + bv.x;
    float oy = (a0.y + a1.y) * rz + bv.y;
    float oz = (a0.z + a1.z) * rz + bv.z;
    float ow = (a0.w + a1.w) * rz + bv.w;
    ox = (ox > 0.f) ? ox : __expf(ox) - 1.f;
    oy = (oy > 0.f) ? oy : __expf(oy) - 1.f;
    oz = (oz > 0.f) ? oz : __expf(oz) - 1.f;
    ow = (ow > 0.f) ? ow : __expf(ow) - 1.f;
    ushort4 o;
    o.x = f2bf(ox); o.y = f2bf(oy); o.z = f2bf(oz); o.w = f2bf(ow);
    *(ushort4*)(out + (size_t)wid * 256 + lane * 4) = o;
}

// ------------------------- GAT aggregation, H=1 (bf16 in/out) -------------

__global__ void gat_agg_h1(const unsigned short* __restrict__ Hpre, const float* __restrict__ w,
                           const int* __restrict__ rowptr, const int* __restrict__ csr_src,
                           const float* __restrict__ bias, unsigned short* __restrict__ out,
                           int N) {
    int wid = (blockIdx.x * blockDim.x + threadIdx.x) >> 6;
    int lane = threadIdx.x & 63;
    if (wid >= N) return;
    const int rs = rowptr[wid], re = rowptr[wid + 1];
    const int half = lane >> 5, c = lane & 31;

    float z = 0.f;
    for (int i = rs + lane; i < re; i += 64) z += w[i];
    z = wave_sum(z);
    const float rz = 1.f / (z + 1e-16f);

    float4 a0 = {0.f, 0.f, 0.f, 0.f}, a1 = {0.f, 0.f, 0.f, 0.f};
    int i = rs + half;
    for (; i < re - 2; i += 4) {
        int s0 = csr_src[i], s1 = csr_src[i + 2];
        float w0 = w[i], w1 = w[i + 2];
        ushort4 u0 = *(const ushort4*)(Hpre + (size_t)s0 * 128 + c * 4);
        ushort4 u1 = *(const ushort4*)(Hpre + (size_t)s1 * 128 + c * 4);
        a0.x += w0 * bf2f(u0.x); a0.y += w0 * bf2f(u0.y);
        a0.z += w0 * bf2f(u0.z); a0.w += w0 * bf2f(u0.w);
        a1.x += w1 * bf2f(u1.x); a1.y += w1 * bf2f(u1.y);
        a1.z += w1 * bf2f(u1.z); a1.w += w1 * bf2f(u1.w);
    }
    if (i < re) {
        int s0 = csr_src[i];
        float w0 = w[i];
        ushort4 u0 = *(const ushort4*)(Hpre + (size_t)s0 * 128 + c * 4);
        a0.x += w0 * bf2f(u0.x); a0.y += w0 * bf2f(u0.y);
        a0.z += w0 * bf2f(u0.z); a0.w += w0 * bf2f(u0.w);
    }
    float ox = a0.x + a1.x, oy = a0.y + a1.y, oz = a0.z + a1.z, ow = a0.w + a1.w;
    ox += __shfl_xor(ox, 32, 64);
    oy += __shfl_xor(oy, 32, 64);
    oz += __shfl_xor(oz, 32, 64);
    ow += __shfl_xor(ow, 32, 64);
    if (lane < 32) {
        float4 bv = ((const float4*)bias)[c];
        ox = ox * rz + bv.x; oy = oy * rz + bv.y; oz = oz * rz + bv.z; ow = ow * rz + bv.w;
        ox = (ox > 0.f) ? ox : __expf(ox) - 1.f;
        oy = (oy > 0.f) ? oy : __expf(oy) - 1.f;
        oz = (oz > 0.f) ? oz : __expf(oz) - 1.f;
        ow = (ow > 0.f) ? ow : __expf(ow) - 1.f;
        ushort4 o;
        o.x = f2bf(ox); o.y = f2bf(oy); o.z = f2bf(oz); o.w = f2bf(ow);
        *(ushort4*)(out + (size_t)wid * 128 + c * 4) = o;
    }
}

// ------------------------- global mean pool (chunk-parallel) --------------
// Grid covers node chunks of 256; batch is sorted, so each thread keeps one
// running (graph, acc) and flushes via atomicAdd on graph change / chunk end.

#define PCHUNK 256

__global__ __launch_bounds__(256) void pool_partial(const unsigned short* __restrict__ h2,
                                                    const int* __restrict__ batch,
                                                    float* __restrict__ xsum,
                                                    int* __restrict__ cnt, int N) {
    const int base = blockIdx.x * PCHUNK;
    const int rg = threadIdx.x >> 6;        // 4 rows in flight
    const int c2 = threadIdx.x & 63;        // channel pair
    float ax = 0.f, ay = 0.f;
    int gcur = -1, run = 0;
    for (int r = rg; r < PCHUNK; r += 4) {
        int i = base + r;
        if (i >= N) break;
        int g = batch[i];
        if (g != gcur) {
            if (gcur >= 0) {
                atomicAdd(&xsum[gcur * 128 + c2 * 2 + 0], ax);
                atomicAdd(&xsum[gcur * 128 + c2 * 2 + 1], ay);
                if (c2 == 0) atomicAdd(&cnt[gcur], run);
            }
            gcur = g; ax = 0.f; ay = 0.f; run = 0;
        }
        ushort2 u = *(const ushort2*)(h2 + (size_t)i * 128 + c2 * 2);
        ax += bf2f(u.x); ay += bf2f(u.y);
        run += 1;
    }
    if (gcur >= 0) {
        atomicAdd(&xsum[gcur * 128 + c2 * 2 + 0], ax);
        atomicAdd(&xsum[gcur * 128 + c2 * 2 + 1], ay);
        if (c2 == 0) atomicAdd(&cnt[gcur], run);
    }
}

// ------------------------- policy / value heads ---------------------------

__global__ void head_kernel(const float* __restrict__ xsum, const int* __restrict__ cnt,
                            const float* __restrict__ Wp, const float* __restrict__ bp,
                            const float* __restrict__ Wv, const float* __restrict__ bv,
                            float* __restrict__ out) {
    int g = blockIdx.x, t = threadIdx.x;  // 64 threads
    __shared__ float p[128];
    float inv = 1.f / fmaxf((float)cnt[g], 1.f);
    p[t] = xsum[g * 128 + t] * inv;
    p[t + 64] = xsum[g * 128 + t + 64] * inv;
    __syncthreads();
    if (t < 32) {
        float acc = bp[t];
        for (int k = 0; k < 128; ++k) acc += p[k] * Wp[k * 32 + t];
        out[g * 32 + t] = acc;
    } else if (t == 32) {
        float acc = bv[0];
        for (int k = 0; k < 128; ++k) acc += p[k] * Wv[k];
        out[64 * 32 + g] = acc;
    }
}

// ---------------------------------------------------------------------------

extern "C" void kernel_launch(void* const* d_in, const int* in_sizes, int n_in,
                              void* d_out, int out_size, void* d_ws, size_t ws_size,
                              hipStream_t stream) {
    const float* x      = (const float*)d_in[0];
    const int*   ei     = (const int*)d_in[1];
    const int*   batch  = (const int*)d_in[2];
    const float* W1     = (const float*)d_in[3];
    const float* a_src1 = (const float*)d_in[4];
    const float* a_dst1 = (const float*)d_in[5];
    const float* b1     = (const float*)d_in[6];
    const float* W2     = (const float*)d_in[7];
    const float* a_src2 = (const float*)d_in[8];
    const float* a_dst2 = (const float*)d_in[9];
    const float* b2     = (const float*)d_in[10];
    const float* Wp     = (const float*)d_in[11];
    const float* bp     = (const float*)d_in[12];
    const float* Wv     = (const float*)d_in[13];
    const float* bv     = (const float*)d_in[14];

    const int N  = in_sizes[0] / 128;
    const int E  = in_sizes[1] / 2;
    const int ET = E + N;
    const int TILES = (N + 1023) / 1024;
    const int NPAD = ((N + 63) / 64) * 64;
    const int NBLK = NPAD / 64;
    const int PBLK = (N + PCHUNK - 1) / PCHUNK;

    char* ws = (char*)d_ws;
    size_t off = 0;
    auto alloc = [&](size_t bytes) -> void* {
        void* p = ws + off;
        off = (off + bytes + 255) & ~(size_t)255;
        return p;
    };
    unsigned short* h1pre = (unsigned short*)alloc((size_t)NPAD * 256 * 2);  // reused as h2pre
    unsigned short* h1bf  = (unsigned short*)alloc((size_t)NPAD * 256 * 2);
    unsigned short* xbf   = (unsigned short*)alloc((size_t)NPAD * 128 * 2);
    unsigned short* h2bf  = (unsigned short*)alloc((size_t)N * 128 * 2);
    unsigned short* w1bf  = (unsigned short*)alloc((size_t)128 * 256 * 2);
    unsigned short* w2bf  = (unsigned short*)alloc((size_t)256 * 128 * 2);
    float* wbuf   = (float*)alloc((size_t)ET * 2 * 4);
    float* es1    = (float*)alloc((size_t)N * 2 * 4);
    float* ed1    = (float*)alloc((size_t)N * 2 * 4);
    float* es2    = (float*)alloc((size_t)N * 4);
    float* ed2    = (float*)alloc((size_t)N * 4);
    int*   deg    = (int*)alloc((size_t)N * 4);
    int*   rowptr = (int*)alloc((size_t)(N + 1) * 4);
    int*   cursor = (int*)alloc((size_t)N * 4);
    int*   csrsrc = (int*)alloc((size_t)ET * 4);
    int*   csrdst = (int*)alloc((size_t)ET * 4);
    int*   tsum   = (int*)alloc(64 * 4);
    int*   toff   = (int*)alloc(64 * 4);
    float* xsum   = (float*)alloc((size_t)64 * 128 * 4 + 64 * 4);  // + cnt, zeroed together
    int*   cnt    = (int*)(xsum + 64 * 128);
    unsigned short* h2pre = h1pre;  // h1pre dead after layer-1 agg

    // --- CSR build ---
    zero_int_kernel<<<(N + 255) / 256, 256, 0, stream>>>(deg, N);
    degree_kernel<<<(ET + 255) / 256, 256, 0, stream>>>(ei, deg, E, N);
    scan_tiles<<<TILES, 256, 0, stream>>>(deg, tsum, N);
    scan_sums<<<1, 64, 0, stream>>>(tsum, toff, rowptr + N, TILES);
    scan_add<<<(N + 255) / 256, 256, 0, stream>>>(deg, toff, rowptr, cursor, N);
    scatter_kernel<<<(ET + 255) / 256, 256, 0, stream>>>(ei, cursor, csrsrc, csrdst, E, N);

    // --- zero pool accumulators (ws is poisoned every call) ---
    zero_int_kernel<<<(64 * 128 + 64 + 255) / 256, 256, 0, stream>>>((int*)xsum, 64 * 128 + 64);

    // --- casts ---
    cast_bf16_kernel<<<(NPAD * 128 / 4 + 255) / 256, 256, 0, stream>>>(x, xbf, N * 128, NPAD * 128);
    cast_bf16_kernel<<<(128 * 256 / 4 + 255) / 256, 256, 0, stream>>>(W1, w1bf, 128 * 256, 128 * 256);
    cast_bf16_kernel<<<(256 * 128 / 4 + 255) / 256, 256, 0, stream>>>(W2, w2bf, 256 * 128, 256 * 128);

    // --- layer 1: heads=2 ---
    gemm_mfma<128, 256><<<NBLK, 256, 0, stream>>>(xbf, w1bf, h1pre, N);
    attn_coef<<<(N * 2 + 3) / 4, 256, 0, stream>>>(h1pre, a_src1, a_dst1, es1, ed1, N, 2);
    edge_w_kernel<2><<<(ET + 255) / 256, 256, 0, stream>>>(es1, ed1, csrsrc, csrdst, wbuf, ET);
    gat_agg_h2<<<(N + 3) / 4, 256, 0, stream>>>(h1pre, wbuf, rowptr, csrsrc, b1, h1bf, N);

    // --- layer 2: heads=1 ---
    gemm_mfma<256, 128><<<NBLK, 256, 0, stream>>>(h1bf, w2bf, h2pre, N);
    attn_coef<<<(N + 3) / 4, 256, 0, stream>>>(h2pre, a_src2, a_dst2, es2, ed2, N, 1);
    edge_w_kernel<1><<<(ET + 255) / 256, 256, 0, stream>>>(es2, ed2, csrsrc, csrdst, wbuf, ET);
    gat_agg_h1<<<(N + 3) / 4, 256, 0, stream>>>(h2pre, wbuf, rowptr, csrsrc, b2, h2bf, N);

    // --- pool + heads ---
    pool_partial<<<PBLK, 256, 0, stream>>>(h2bf, batch, xsum, cnt, N);
    head_kernel<<<64, 64, 0, stream>>>(xsum, cnt, Wp, bp, Wv, bv, (float*)d_out);
}

// Round 6
// 409.769 us; speedup vs baseline: 2.3884x; 1.0416x over previous
//
#include <hip/hip_runtime.h>
#include <hip/hip_bf16.h>
#include <cstdint>

// ---------------------------------------------------------------------------
// GraphRLAgent: 2-layer GAT (heads=2 then 1) + global mean pool + 2 heads.
// Round 6:
//  - swizzled-B prep kernel: GEMM B-frags load as 16 coalesced 16B vectors
//    (was 128 scalar 2B strided loads); weight cast kernels folded in.
//  - edge_w fused into gat_agg pass-1 (csr_dst eliminated, 2 fewer kernels).
//  - pass-2 gather unrolled to 4 edges in flight.
// ---------------------------------------------------------------------------

typedef __attribute__((ext_vector_type(8))) short bf16x8;
typedef __attribute__((ext_vector_type(4))) float f32x4;

__device__ __forceinline__ float wave_sum(float v) {
#pragma unroll
    for (int off = 32; off >= 1; off >>= 1) v += __shfl_xor(v, off, 64);
    return v;
}

__device__ __forceinline__ unsigned short f2bf(float f) {
    union { float f; uint32_t u; } c; c.f = f;
    uint32_t u = c.u;
    return (unsigned short)((u + 0x7fffu + ((u >> 16) & 1u)) >> 16);
}

__device__ __forceinline__ float bf2f(unsigned short u) {
    union { uint32_t u; float f; } c; c.u = ((uint32_t)u) << 16;
    return c.f;
}

// ------------------------- CSR construction -------------------------------

__global__ void zero_int_kernel(int* __restrict__ p, int n) {
    int i = blockIdx.x * blockDim.x + threadIdx.x;
    if (i < n) p[i] = 0;
}

__global__ void degree_kernel(const int* __restrict__ ei, int* __restrict__ deg,
                              int E, int N) {
    int i = blockIdx.x * blockDim.x + threadIdx.x;
    if (i >= E + N) return;
    int dst = (i < E) ? ei[E + i] : (i - E);
    atomicAdd(&deg[dst], 1);
}

__global__ __launch_bounds__(256) void scan_tiles(int* __restrict__ deg,
                                                  int* __restrict__ tsum, int N) {
    __shared__ int buf[256];
    const int t = threadIdx.x;
    const int base = blockIdx.x * 1024 + t * 4;
    int v[4]; int s = 0;
#pragma unroll
    for (int k = 0; k < 4; ++k) { v[k] = (base + k < N) ? deg[base + k] : 0; s += v[k]; }
    buf[t] = s;
    __syncthreads();
#pragma unroll
    for (int off = 1; off < 256; off <<= 1) {
        int x = (t >= off) ? buf[t - off] : 0;
        __syncthreads();
        buf[t] += x;
        __syncthreads();
    }
    int run = buf[t] - s;
#pragma unroll
    for (int k = 0; k < 4; ++k) {
        if (base + k < N) deg[base + k] = run;
        run += v[k];
    }
    if (t == 255) tsum[blockIdx.x] = buf[255];
}

__global__ void scan_sums(int* __restrict__ tsum, int* __restrict__ toff,
                          int* __restrict__ rowptrN, int T) {
    int t = threadIdx.x;  // 64 threads
    int v = (t < T) ? tsum[t] : 0;
    int orig = v;
#pragma unroll
    for (int off = 1; off < 64; off <<= 1) {
        int x = __shfl_up(v, off, 64);
        if (t >= off) v += x;
    }
    if (t < T) toff[t] = v - orig;
    if (t == 63) *rowptrN = v;
}

__global__ void scan_add(const int* __restrict__ partial, const int* __restrict__ toff,
                         int* __restrict__ rowptr, int* __restrict__ cursor, int N) {
    int i = blockIdx.x * blockDim.x + threadIdx.x;
    if (i < N) {
        int r = partial[i] + toff[i >> 10];
        rowptr[i] = r;
        cursor[i] = r;
    }
}

__global__ void scatter_kernel(const int* __restrict__ ei, int* __restrict__ cursor,
                               int* __restrict__ csr_src, int E, int N) {
    int i = blockIdx.x * blockDim.x + threadIdx.x;
    if (i >= E + N) return;
    int src, dst;
    if (i < E) { src = ei[i]; dst = ei[E + i]; }
    else       { src = dst = i - E; }
    int pos = atomicAdd(&cursor[dst], 1);
    csr_src[pos] = src;
}

// ------------------------- fp32 -> bf16 cast (zero-padded) ----------------

__global__ void cast_bf16_kernel(const float* __restrict__ src, unsigned short* __restrict__ dst,
                                 int n, int npad) {
    int i = (blockIdx.x * blockDim.x + threadIdx.x) * 4;
    if (i >= npad) return;
    float a, b, c, d;
    if (i + 3 < n) {
        float4 v = *(const float4*)(src + i);
        a = v.x; b = v.y; c = v.z; d = v.w;
    } else {
        a = (i + 0 < n) ? src[i + 0] : 0.f;
        b = (i + 1 < n) ? src[i + 1] : 0.f;
        c = (i + 2 < n) ? src[i + 2] : 0.f;
        d = (i + 3 < n) ? src[i + 3] : 0.f;
    }
    ushort4 o;
    o.x = f2bf(a); o.y = f2bf(b); o.z = f2bf(c); o.w = f2bf(d);
    *(ushort4*)(dst + i) = o;
}

// ------------------------- B swizzle (fp32 W -> frag-ordered bf16) --------
// One thread per bf16x8 fragment. Output unit index (16B granules):
//   tid = ((cg*NCT + c)*KST + t)*64 + lane,  lane = quad*16 + lo
//   frag[j] = W[(t*32 + quad*8 + j)*FOUT + cg*CPW + c*16 + lo]
// matching gemm_mfma's per-wave fragment load Bp[((wave*NCT+c)*KST+t)*64+lane].

template <int K, int FOUT>
__global__ void swizzle_B(const float* __restrict__ W, unsigned short* __restrict__ Bsw) {
    constexpr int CPW = FOUT / 4, NCT = CPW / 16, KST = K / 32;
    int tid = blockIdx.x * blockDim.x + threadIdx.x;
    if (tid >= K * FOUT / 8) return;
    int lane = tid & 63;
    int rest = tid >> 6;
    int t = rest % KST; rest /= KST;
    int c = rest % NCT; rest /= NCT;
    int cg = rest;
    int quad = lane >> 4, lo = lane & 15;
    int col = cg * CPW + c * 16 + lo;
    unsigned short v[8];
#pragma unroll
    for (int j = 0; j < 8; ++j)
        v[j] = f2bf(W[(t * 32 + quad * 8 + j) * FOUT + col]);
    ushort4* dst = (ushort4*)(Bsw + (size_t)tid * 8);
    ushort4 o0, o1;
    o0.x = v[0]; o0.y = v[1]; o0.z = v[2]; o0.w = v[3];
    o1.x = v[4]; o1.y = v[5]; o1.z = v[6]; o1.w = v[7];
    dst[0] = o0; dst[1] = o1;
}

// ------------------------- bf16 MFMA GEMM (bf16 out, swizzled B) ----------

template <int K, int FOUT>
__global__ __launch_bounds__(256) void gemm_mfma(const unsigned short* __restrict__ A,
                                                 const unsigned short* __restrict__ Bsw,
                                                 unsigned short* __restrict__ C, int N) {
    constexpr int CPW = FOUT / 4;
    constexpr int NCT = CPW / 16;
    constexpr int KST = K / 32;
    const int tid = threadIdx.x;
    const int wave = tid >> 6, lane = tid & 63;
    const int quad = lane >> 4, lo = lane & 15;
    const int n0 = blockIdx.x * 64;
    const int c0 = wave * CPW;

    bf16x8 bf[NCT][KST];
    {
        const bf16x8* Bp = (const bf16x8*)Bsw;
#pragma unroll
        for (int c = 0; c < NCT; ++c)
#pragma unroll
            for (int t = 0; t < KST; ++t)
                bf[c][t] = Bp[((wave * NCT + c) * KST + t) * 64 + lane];
    }

    f32x4 acc[4][NCT];
#pragma unroll
    for (int r = 0; r < 4; ++r)
#pragma unroll
        for (int c = 0; c < NCT; ++c) acc[r][c] = (f32x4){0.f, 0.f, 0.f, 0.f};

#pragma unroll
    for (int r = 0; r < 4; ++r) {
        const unsigned short* Ar = A + (size_t)(n0 + r * 16 + lo) * K + quad * 8;
#pragma unroll
        for (int t = 0; t < KST; ++t) {
            bf16x8 af = *(const bf16x8*)(Ar + t * 32);
#pragma unroll
            for (int c = 0; c < NCT; ++c)
                acc[r][c] = __builtin_amdgcn_mfma_f32_16x16x32_bf16(af, bf[c][t], acc[r][c],
                                                                   0, 0, 0);
        }
    }

    // C/D layout: col = lane&15, row = quad*4 + j
#pragma unroll
    for (int r = 0; r < 4; ++r) {
        int row = n0 + r * 16 + quad * 4;
#pragma unroll
        for (int c = 0; c < NCT; ++c) {
            int col = c0 + c * 16 + lo;
#pragma unroll
            for (int j = 0; j < 4; ++j)
                if (row + j < N) C[(size_t)(row + j) * FOUT + col] = f2bf(acc[r][c][j]);
        }
    }
}

// ------------------------- attention coefficients (bf16 in) ---------------

__global__ void attn_coef(const unsigned short* __restrict__ Hpre, const float* __restrict__ a_src,
                          const float* __restrict__ a_dst, float* __restrict__ es,
                          float* __restrict__ ed, int N, int H) {
    int wid = (blockIdx.x * blockDim.x + threadIdx.x) >> 6;
    int lane = threadIdx.x & 63;
    if (wid >= N * H) return;
    int h = wid % H;
    const unsigned short* hp = Hpre + (size_t)wid * 128;
    const float* as = a_src + h * 128;
    const float* ad = a_dst + h * 128;
    float v0 = bf2f(hp[lane]), v1 = bf2f(hp[lane + 64]);
    float ps = v0 * as[lane] + v1 * as[lane + 64];
    float pd = v0 * ad[lane] + v1 * ad[lane + 64];
    ps = wave_sum(ps);
    pd = wave_sum(pd);
    if (lane == 0) { es[wid] = ps; ed[wid] = pd; }
}

// ------------------------- GAT aggregation, H=2 (fused softmax) -----------
// Pass 1: lanes walk edges, compute w = exp(leaky_relu(es[src]+ed[n])),
// write w (coalesced) and reduce z. Fence. Pass 2: 4-edge-unrolled gather.

__global__ void gat_agg_h2(const unsigned short* __restrict__ Hpre,
                           const float* __restrict__ es, const float* __restrict__ ed,
                           float* __restrict__ w,
                           const int* __restrict__ rowptr, const int* __restrict__ csr_src,
                           const float* __restrict__ bias, unsigned short* __restrict__ out,
                           int N) {
    int wid = (blockIdx.x * blockDim.x + threadIdx.x) >> 6;
    int lane = threadIdx.x & 63;
    if (wid >= N) return;
    const int rs = rowptr[wid], re = rowptr[wid + 1];
    const int h = lane >> 5;
    const float edn = ed[wid * 2 + h];

    float z = 0.f;
    for (int i = rs + (lane & 31); i < re; i += 32) {
        int s = csr_src[i];
        float e = es[s * 2 + h] + edn;
        e = (e > 0.f) ? e : 0.2f * e;
        float ww = __expf(e);
        z += ww;
        w[i * 2 + h] = ww;
    }
#pragma unroll
    for (int off = 16; off >= 1; off >>= 1) z += __shfl_xor(z, off, 64);
    const float rz = 1.f / (z + 1e-16f);
    __threadfence_block();  // drain vmcnt: same-wave RAW on w through L1/L2

    float4 a0 = {0.f, 0.f, 0.f, 0.f}, a1 = {0.f, 0.f, 0.f, 0.f};
    float4 a2 = {0.f, 0.f, 0.f, 0.f}, a3 = {0.f, 0.f, 0.f, 0.f};
    int i = rs;
    for (; i + 4 <= re; i += 4) {
        int s0 = csr_src[i], s1 = csr_src[i + 1], s2 = csr_src[i + 2], s3 = csr_src[i + 3];
        float w0 = w[i * 2 + h], w1 = w[i * 2 + 2 + h];
        float w2 = w[i * 2 + 4 + h], w3 = w[i * 2 + 6 + h];
        ushort4 u0 = *(const ushort4*)(Hpre + (size_t)s0 * 256 + lane * 4);
        ushort4 u1 = *(const ushort4*)(Hpre + (size_t)s1 * 256 + lane * 4);
        ushort4 u2 = *(const ushort4*)(Hpre + (size_t)s2 * 256 + lane * 4);
        ushort4 u3 = *(const ushort4*)(Hpre + (size_t)s3 * 256 + lane * 4);
        a0.x += w0 * bf2f(u0.x); a0.y += w0 * bf2f(u0.y);
        a0.z += w0 * bf2f(u0.z); a0.w += w0 * bf2f(u0.w);
        a1.x += w1 * bf2f(u1.x); a1.y += w1 * bf2f(u1.y);
        a1.z += w1 * bf2f(u1.z); a1.w += w1 * bf2f(u1.w);
        a2.x += w2 * bf2f(u2.x); a2.y += w2 * bf2f(u2.y);
        a2.z += w2 * bf2f(u2.z); a2.w += w2 * bf2f(u2.w);
        a3.x += w3 * bf2f(u3.x); a3.y += w3 * bf2f(u3.y);
        a3.z += w3 * bf2f(u3.z); a3.w += w3 * bf2f(u3.w);
    }
    for (; i < re; ++i) {
        int s0 = csr_src[i];
        float w0 = w[i * 2 + h];
        ushort4 u0 = *(const ushort4*)(Hpre + (size_t)s0 * 256 + lane * 4);
        a0.x += w0 * bf2f(u0.x); a0.y += w0 * bf2f(u0.y);
        a0.z += w0 * bf2f(u0.z); a0.w += w0 * bf2f(u0.w);
    }
    float4 bv = ((const float4*)bias)[lane];
    float ox = (a0.x + a1.x + a2.x + a3.x) * rz + bv.x;
    float oy = (a0.y + a1.y + a2.y + a3.y) * rz + bv.y;
    float oz = (a0.z + a1.z + a2.z + a3.z) * rz + bv.z;
    float ow = (a0.w + a1.w + a2.w + a3.w) * rz + bv.w;
    ox = (ox > 0.f) ? ox : __expf(ox) - 1.f;
    oy = (oy > 0.f) ? oy : __expf(oy) - 1.f;
    oz = (oz > 0.f) ? oz : __expf(oz) - 1.f;
    ow = (ow > 0.f) ? ow : __expf(ow) - 1.f;
    ushort4 o;
    o.x = f2bf(ox); o.y = f2bf(oy); o.z = f2bf(oz); o.w = f2bf(ow);
    *(ushort4*)(out + (size_t)wid * 256 + lane * 4) = o;
}

// ------------------------- GAT aggregation, H=1 (fused softmax) -----------
// Pass 2: half-wave per edge, 4 edges per half (8 in flight per wave).

__global__ void gat_agg_h1(const unsigned short* __restrict__ Hpre,
                           const float* __restrict__ es, const float* __restrict__ ed,
                           float* __restrict__ w,
                           const int* __restrict__ rowptr, const int* __restrict__ csr_src,
                           const float* __restrict__ bias, unsigned short* __restrict__ out,
                           int N) {
    int wid = (blockIdx.x * blockDim.x + threadIdx.x) >> 6;
    int lane = threadIdx.x & 63;
    if (wid >= N) return;
    const int rs = rowptr[wid], re = rowptr[wid + 1];
    const int half = lane >> 5, c = lane & 31;
    const float edn = ed[wid];

    float z = 0.f;
    for (int i = rs + lane; i < re; i += 64) {
        int s = csr_src[i];
        float e = es[s] + edn;
        e = (e > 0.f) ? e : 0.2f * e;
        float ww = __expf(e);
        z += ww;
        w[i] = ww;
    }
    z = wave_sum(z);
    const float rz = 1.f / (z + 1e-16f);
    __threadfence_block();  // drain vmcnt: same-wave RAW on w

    float4 a0 = {0.f, 0.f, 0.f, 0.f}, a1 = {0.f, 0.f, 0.f, 0.f};
    float4 a2 = {0.f, 0.f, 0.f, 0.f}, a3 = {0.f, 0.f, 0.f, 0.f};
    int i = rs + half;
    for (; i + 6 < re; i += 8) {
        int s0 = csr_src[i], s1 = csr_src[i + 2], s2 = csr_src[i + 4], s3 = csr_src[i + 6];
        float w0 = w[i], w1 = w[i + 2], w2 = w[i + 4], w3 = w[i + 6];
        ushort4 u0 = *(const ushort4*)(Hpre + (size_t)s0 * 128 + c * 4);
        ushort4 u1 = *(const ushort4*)(Hpre + (size_t)s1 * 128 + c * 4);
        ushort4 u2 = *(const ushort4*)(Hpre + (size_t)s2 * 128 + c * 4);
        ushort4 u3 = *(const ushort4*)(Hpre + (size_t)s3 * 128 + c * 4);
        a0.x += w0 * bf2f(u0.x); a0.y += w0 * bf2f(u0.y);
        a0.z += w0 * bf2f(u0.z); a0.w += w0 * bf2f(u0.w);
        a1.x += w1 * bf2f(u1.x); a1.y += w1 * bf2f(u1.y);
        a1.z += w1 * bf2f(u1.z); a1.w += w1 * bf2f(u1.w);
        a2.x += w2 * bf2f(u2.x); a2.y += w2 * bf2f(u2.y);
        a2.z += w2 * bf2f(u2.z); a2.w += w2 * bf2f(u2.w);
        a3.x += w3 * bf2f(u3.x); a3.y += w3 * bf2f(u3.y);
        a3.z += w3 * bf2f(u3.z); a3.w += w3 * bf2f(u3.w);
    }
    for (; i < re; i += 2) {
        int s0 = csr_src[i];
        float w0 = w[i];
        ushort4 u0 = *(const ushort4*)(Hpre + (size_t)s0 * 128 + c * 4);
        a0.x += w0 * bf2f(u0.x); a0.y += w0 * bf2f(u0.y);
        a0.z += w0 * bf2f(u0.z); a0.w += w0 * bf2f(u0.w);
    }
    float ox = a0.x + a1.x + a2.x + a3.x;
    float oy = a0.y + a1.y + a2.y + a3.y;
    float oz = a0.z + a1.z + a2.z + a3.z;
    float ow = a0.w + a1.w + a2.w + a3.w;
    ox += __shfl_xor(ox, 32, 64);
    oy += __shfl_xor(oy, 32, 64);
    oz += __shfl_xor(oz, 32, 64);
    ow += __shfl_xor(ow, 32, 64);
    if (lane < 32) {
        float4 bv = ((const float4*)bias)[c];
        ox = ox * rz + bv.x; oy = oy * rz + bv.y; oz = oz * rz + bv.z; ow = ow * rz + bv.w;
        ox = (ox > 0.f) ? ox : __expf(ox) - 1.f;
        oy = (oy > 0.f) ? oy : __expf(oy) - 1.f;
        oz = (oz > 0.f) ? oz : __expf(oz) - 1.f;
        ow = (ow > 0.f) ? ow : __expf(ow) - 1.f;
        ushort4 o;
        o.x = f2bf(ox); o.y = f2bf(oy); o.z = f2bf(oz); o.w = f2bf(ow);
        *(ushort4*)(out + (size_t)wid * 128 + c * 4) = o;
    }
}

// ------------------------- global mean pool (chunk-parallel) --------------

#define PCHUNK 256

__global__ __launch_bounds__(256) void pool_partial(const unsigned short* __restrict__ h2,
                                                    const int* __restrict__ batch,
                                                    float* __restrict__ xsum,
                                                    int* __restrict__ cnt, int N) {
    const int base = blockIdx.x * PCHUNK;
    const int rg = threadIdx.x >> 6;
    const int c2 = threadIdx.x & 63;
    float ax = 0.f, ay = 0.f;
    int gcur = -1, run = 0;
    for (int r = rg; r < PCHUNK; r += 4) {
        int i = base + r;
        if (i >= N) break;
        int g = batch[i];
        if (g != gcur) {
            if (gcur >= 0) {
                atomicAdd(&xsum[gcur * 128 + c2 * 2 + 0], ax);
                atomicAdd(&xsum[gcur * 128 + c2 * 2 + 1], ay);
                if (c2 == 0) atomicAdd(&cnt[gcur], run);
            }
            gcur = g; ax = 0.f; ay = 0.f; run = 0;
        }
        ushort2 u = *(const ushort2*)(h2 + (size_t)i * 128 + c2 * 2);
        ax += bf2f(u.x); ay += bf2f(u.y);
        run += 1;
    }
    if (gcur >= 0) {
        atomicAdd(&xsum[gcur * 128 + c2 * 2 + 0], ax);
        atomicAdd(&xsum[gcur * 128 + c2 * 2 + 1], ay);
        if (c2 == 0) atomicAdd(&cnt[gcur], run);
    }
}

// ------------------------- policy / value heads ---------------------------

__global__ void head_kernel(const float* __restrict__ xsum, const int* __restrict__ cnt,
                            const float* __restrict__ Wp, const float* __restrict__ bp,
                            const float* __restrict__ Wv, const float* __restrict__ bv,
                            float* __restrict__ out) {
    int g = blockIdx.x, t = threadIdx.x;  // 64 threads
    __shared__ float p[128];
    float inv = 1.f / fmaxf((float)cnt[g], 1.f);
    p[t] = xsum[g * 128 + t] * inv;
    p[t + 64] = xsum[g * 128 + t + 64] * inv;
    __syncthreads();
    if (t < 32) {
        float acc = bp[t];
        for (int k = 0; k < 128; ++k) acc += p[k] * Wp[k * 32 + t];
        out[g * 32 + t] = acc;
    } else if (t == 32) {
        float acc = bv[0];
        for (int k = 0; k < 128; ++k) acc += p[k] * Wv[k];
        out[64 * 32 + g] = acc;
    }
}

// ---------------------------------------------------------------------------

extern "C" void kernel_launch(void* const* d_in, const int* in_sizes, int n_in,
                              void* d_out, int out_size, void* d_ws, size_t ws_size,
                              hipStream_t stream) {
    const float* x      = (const float*)d_in[0];
    const int*   ei     = (const int*)d_in[1];
    const int*   batch  = (const int*)d_in[2];
    const float* W1     = (const float*)d_in[3];
    const float* a_src1 = (const float*)d_in[4];
    const float* a_dst1 = (const float*)d_in[5];
    const float* b1     = (const float*)d_in[6];
    const float* W2     = (const float*)d_in[7];
    const float* a_src2 = (const float*)d_in[8];
    const float* a_dst2 = (const float*)d_in[9];
    const float* b2     = (const float*)d_in[10];
    const float* Wp     = (const float*)d_in[11];
    const float* bp     = (const float*)d_in[12];
    const float* Wv     = (const float*)d_in[13];
    const float* bv     = (const float*)d_in[14];

    const int N  = in_sizes[0] / 128;
    const int E  = in_sizes[1] / 2;
    const int ET = E + N;
    const int TILES = (N + 1023) / 1024;
    const int NPAD = ((N + 63) / 64) * 64;
    const int NBLK = NPAD / 64;
    const int PBLK = (N + PCHUNK - 1) / PCHUNK;

    char* ws = (char*)d_ws;
    size_t off = 0;
    auto alloc = [&](size_t bytes) -> void* {
        void* p = ws + off;
        off = (off + bytes + 255) & ~(size_t)255;
        return p;
    };
    unsigned short* h1pre = (unsigned short*)alloc((size_t)NPAD * 256 * 2);  // reused as h2pre
    unsigned short* h1bf  = (unsigned short*)alloc((size_t)NPAD * 256 * 2);
    unsigned short* xbf   = (unsigned short*)alloc((size_t)NPAD * 128 * 2);
    unsigned short* h2bf  = (unsigned short*)alloc((size_t)N * 128 * 2);
    unsigned short* w1sw  = (unsigned short*)alloc((size_t)128 * 256 * 2);
    unsigned short* w2sw  = (unsigned short*)alloc((size_t)256 * 128 * 2);
    float* wbuf   = (float*)alloc((size_t)ET * 2 * 4);
    float* es1    = (float*)alloc((size_t)N * 2 * 4);
    float* ed1    = (float*)alloc((size_t)N * 2 * 4);
    float* es2    = (float*)alloc((size_t)N * 4);
    float* ed2    = (float*)alloc((size_t)N * 4);
    int*   deg    = (int*)alloc((size_t)N * 4);
    int*   rowptr = (int*)alloc((size_t)(N + 1) * 4);
    int*   cursor = (int*)alloc((size_t)N * 4);
    int*   csrsrc = (int*)alloc((size_t)ET * 4);
    int*   tsum   = (int*)alloc(64 * 4);
    int*   toff   = (int*)alloc(64 * 4);
    float* xsum   = (float*)alloc((size_t)64 * 128 * 4 + 64 * 4);  // + cnt, zeroed together
    int*   cnt    = (int*)(xsum + 64 * 128);
    unsigned short* h2pre = h1pre;  // h1pre dead after layer-1 agg

    // --- CSR build ---
    zero_int_kernel<<<(N + 255) / 256, 256, 0, stream>>>(deg, N);
    degree_kernel<<<(ET + 255) / 256, 256, 0, stream>>>(ei, deg, E, N);
    scan_tiles<<<TILES, 256, 0, stream>>>(deg, tsum, N);
    scan_sums<<<1, 64, 0, stream>>>(tsum, toff, rowptr + N, TILES);
    scan_add<<<(N + 255) / 256, 256, 0, stream>>>(deg, toff, rowptr, cursor, N);
    scatter_kernel<<<(ET + 255) / 256, 256, 0, stream>>>(ei, cursor, csrsrc, E, N);

    // --- zero pool accumulators (ws is poisoned every call) ---
    zero_int_kernel<<<(64 * 128 + 64 + 255) / 256, 256, 0, stream>>>((int*)xsum, 64 * 128 + 64);

    // --- input cast + weight swizzles ---
    cast_bf16_kernel<<<(NPAD * 128 / 4 + 255) / 256, 256, 0, stream>>>(x, xbf, N * 128, NPAD * 128);
    swizzle_B<128, 256><<<(128 * 256 / 8 + 255) / 256, 256, 0, stream>>>(W1, w1sw);
    swizzle_B<256, 128><<<(256 * 128 / 8 + 255) / 256, 256, 0, stream>>>(W2, w2sw);

    // --- layer 1: heads=2 ---
    gemm_mfma<128, 256><<<NBLK, 256, 0, stream>>>(xbf, w1sw, h1pre, N);
    attn_coef<<<(N * 2 + 3) / 4, 256, 0, stream>>>(h1pre, a_src1, a_dst1, es1, ed1, N, 2);
    gat_agg_h2<<<(N + 3) / 4, 256, 0, stream>>>(h1pre, es1, ed1, wbuf, rowptr, csrsrc, b1,
                                                h1bf, N);

    // --- layer 2: heads=1 ---
    gemm_mfma<256, 128><<<NBLK, 256, 0, stream>>>(h1bf, w2sw, h2pre, N);
    attn_coef<<<(N + 3) / 4, 256, 0, stream>>>(h2pre, a_src2, a_dst2, es2, ed2, N, 1);
    gat_agg_h1<<<(N + 3) / 4, 256, 0, stream>>>(h2pre, es2, ed2, wbuf, rowptr, csrsrc, b2,
                                                h2bf, N);

    // --- pool + heads ---
    pool_partial<<<PBLK, 256, 0, stream>>>(h2bf, batch, xsum, cnt, N);
    head_kernel<<<64, 64, 0, stream>>>(xsum, cnt, Wp, bp, Wv, bv, (float*)d_out);
}

// Round 7
// 392.688 us; speedup vs baseline: 2.4923x; 1.0435x over previous
//
#include <hip/hip_runtime.h>
#include <hip/hip_bf16.h>
#include <cstdint>

// ---------------------------------------------------------------------------
// GraphRLAgent: 2-layer GAT (heads=2 then 1) + global mean pool + 2 heads.
// Round 7 (tail compaction): attn_coef fused into GEMM epilogue (atomicAdd
// es/ed from fp32 acc), x-cast fused into GEMM1 A-load, single zero launch,
// scan_sums folded into scan_add, both swizzles in one launch. 12 dispatches.
// ---------------------------------------------------------------------------

typedef __attribute__((ext_vector_type(8))) short bf16x8;
typedef __attribute__((ext_vector_type(4))) float f32x4;

__device__ __forceinline__ float wave_sum(float v) {
#pragma unroll
    for (int off = 32; off >= 1; off >>= 1) v += __shfl_xor(v, off, 64);
    return v;
}

__device__ __forceinline__ unsigned short f2bf(float f) {
    union { float f; uint32_t u; } c; c.f = f;
    uint32_t u = c.u;
    return (unsigned short)((u + 0x7fffu + ((u >> 16) & 1u)) >> 16);
}

__device__ __forceinline__ float bf2f(unsigned short u) {
    union { uint32_t u; float f; } c; c.u = ((uint32_t)u) << 16;
    return c.f;
}

// ------------------------- zero (int4) ------------------------------------

__global__ void zero4_kernel(int* __restrict__ p, int n4) {
    int i = blockIdx.x * blockDim.x + threadIdx.x;
    if (i < n4) ((int4*)p)[i] = make_int4(0, 0, 0, 0);
}

// ------------------------- CSR construction -------------------------------

__global__ void degree_kernel(const int* __restrict__ ei, int* __restrict__ deg,
                              int E, int N) {
    int i = blockIdx.x * blockDim.x + threadIdx.x;
    if (i >= E + N) return;
    int dst = (i < E) ? ei[E + i] : (i - E);
    atomicAdd(&deg[dst], 1);
}

__global__ __launch_bounds__(256) void scan_tiles(int* __restrict__ deg,
                                                  int* __restrict__ tsum, int N) {
    __shared__ int buf[256];
    const int t = threadIdx.x;
    const int base = blockIdx.x * 1024 + t * 4;
    int v[4]; int s = 0;
#pragma unroll
    for (int k = 0; k < 4; ++k) { v[k] = (base + k < N) ? deg[base + k] : 0; s += v[k]; }
    buf[t] = s;
    __syncthreads();
#pragma unroll
    for (int off = 1; off < 256; off <<= 1) {
        int x = (t >= off) ? buf[t - off] : 0;
        __syncthreads();
        buf[t] += x;
        __syncthreads();
    }
    int run = buf[t] - s;
#pragma unroll
    for (int k = 0; k < 4; ++k) {
        if (base + k < N) deg[base + k] = run;
        run += v[k];
    }
    if (t == 255) tsum[blockIdx.x] = buf[255];
}

// one block per 1024-node tile; re-scans the <=64 tile sums in-wave (fuses the
// old scan_sums kernel), then adds the tile offset to the tile-local prefixes.
__global__ __launch_bounds__(256) void scan_add(const int* __restrict__ partial,
                                                const int* __restrict__ tsum,
                                                int* __restrict__ rowptr,
                                                int* __restrict__ cursor, int N, int T) {
    __shared__ int s_toff;
    const int tile = blockIdx.x;
    if (threadIdx.x < 64) {
        int t = threadIdx.x;
        int v = (t < T) ? tsum[t] : 0;
#pragma unroll
        for (int off = 1; off < 64; off <<= 1) {
            int x = __shfl_up(v, off, 64);
            if (t >= off) v += x;
        }
        int toff = (tile == 0) ? 0 : __shfl(v, tile - 1, 64);
        if (t == 0) s_toff = toff;
        if (tile == 0 && t == 63) rowptr[N] = v;  // grand total (inclusive of all T)
    }
    __syncthreads();
    const int toff = s_toff;
    int i = tile * 1024 + threadIdx.x * 4;
#pragma unroll
    for (int k = 0; k < 4; ++k) {
        if (i + k < N) {
            int r = partial[i + k] + toff;
            rowptr[i + k] = r;
            cursor[i + k] = r;
        }
    }
}

__global__ void scatter_kernel(const int* __restrict__ ei, int* __restrict__ cursor,
                               int* __restrict__ csr_src, int E, int N) {
    int i = blockIdx.x * blockDim.x + threadIdx.x;
    if (i >= E + N) return;
    int src, dst;
    if (i < E) { src = ei[i]; dst = ei[E + i]; }
    else       { src = dst = i - E; }
    int pos = atomicAdd(&cursor[dst], 1);
    csr_src[pos] = src;
}

// ------------------------- B swizzle (fp32 W -> frag-ordered bf16) --------

template <int K, int FOUT>
__device__ __forceinline__ void swizzle_body(const float* __restrict__ W,
                                             unsigned short* __restrict__ Bsw, int tid) {
    constexpr int CPW = FOUT / 4, NCT = CPW / 16, KST = K / 32;
    if (tid >= K * FOUT / 8) return;
    int lane = tid & 63;
    int rest = tid >> 6;
    int t = rest % KST; rest /= KST;
    int c = rest % NCT; rest /= NCT;
    int cg = rest;
    int quad = lane >> 4, lo = lane & 15;
    int col = cg * CPW + c * 16 + lo;
    unsigned short v[8];
#pragma unroll
    for (int j = 0; j < 8; ++j)
        v[j] = f2bf(W[(t * 32 + quad * 8 + j) * FOUT + col]);
    ushort4* dst = (ushort4*)(Bsw + (size_t)tid * 8);
    ushort4 o0, o1;
    o0.x = v[0]; o0.y = v[1]; o0.z = v[2]; o0.w = v[3];
    o1.x = v[4]; o1.y = v[5]; o1.z = v[6]; o1.w = v[7];
    dst[0] = o0; dst[1] = o1;
}

__global__ void swizzle_both(const float* __restrict__ W1, const float* __restrict__ W2,
                             unsigned short* __restrict__ B1, unsigned short* __restrict__ B2) {
    int b = blockIdx.x;
    if (b < 16) swizzle_body<128, 256>(W1, B1, b * 256 + threadIdx.x);
    else        swizzle_body<256, 128>(W2, B2, (b - 16) * 256 + threadIdx.x);
}

// ------------------------- bf16 MFMA GEMM + fused attn coef ---------------
// C[N,FOUT](bf16) = A x B, fp32 acc. A is fp32 (A32=true, converted in-reg)
// or bf16. Epilogue: es[row,h] += dot(acc_row, a_src), same for ed, via
// 16-lane shfl reduction + one atomicAdd per row (es/ed pre-zeroed).

template <int K, int FOUT, int H, bool A32>
__global__ __launch_bounds__(256) void gemm_mfma(const void* __restrict__ Av,
                                                 const unsigned short* __restrict__ Bsw,
                                                 const float* __restrict__ a_src,
                                                 const float* __restrict__ a_dst,
                                                 float* __restrict__ es, float* __restrict__ ed,
                                                 unsigned short* __restrict__ C, int N) {
    constexpr int CPW = FOUT / 4;
    constexpr int NCT = CPW / 16;
    constexpr int KST = K / 32;
    const int tid = threadIdx.x;
    const int wave = tid >> 6, lane = tid & 63;
    const int quad = lane >> 4, lo = lane & 15;
    const int n0 = blockIdx.x * 64;
    const int c0 = wave * CPW;

    bf16x8 bf[NCT][KST];
    {
        const bf16x8* Bp = (const bf16x8*)Bsw;
#pragma unroll
        for (int c = 0; c < NCT; ++c)
#pragma unroll
            for (int t = 0; t < KST; ++t)
                bf[c][t] = Bp[((wave * NCT + c) * KST + t) * 64 + lane];
    }

    f32x4 acc[4][NCT];
#pragma unroll
    for (int r = 0; r < 4; ++r)
#pragma unroll
        for (int c = 0; c < NCT; ++c) acc[r][c] = (f32x4){0.f, 0.f, 0.f, 0.f};

#pragma unroll
    for (int r = 0; r < 4; ++r) {
        const int arow = n0 + r * 16 + lo;
        if (A32) {
            const size_t rclamp = (arow < N) ? (size_t)arow : 0;  // stay in-bounds
            const float* Ar = (const float*)Av + rclamp * K + quad * 8;
            const bool valid = arow < N;
#pragma unroll
            for (int t = 0; t < KST; ++t) {
                bf16x8 af;
                if (valid) {
                    float4 v0 = *(const float4*)(Ar + t * 32);
                    float4 v1 = *(const float4*)(Ar + t * 32 + 4);
                    af[0] = (short)f2bf(v0.x); af[1] = (short)f2bf(v0.y);
                    af[2] = (short)f2bf(v0.z); af[3] = (short)f2bf(v0.w);
                    af[4] = (short)f2bf(v1.x); af[5] = (short)f2bf(v1.y);
                    af[6] = (short)f2bf(v1.z); af[7] = (short)f2bf(v1.w);
                } else {
                    af = (bf16x8){0, 0, 0, 0, 0, 0, 0, 0};
                }
#pragma unroll
                for (int c = 0; c < NCT; ++c)
                    acc[r][c] = __builtin_amdgcn_mfma_f32_16x16x32_bf16(af, bf[c][t], acc[r][c],
                                                                       0, 0, 0);
            }
        } else {
            const unsigned short* Ar = (const unsigned short*)Av + (size_t)arow * K + quad * 8;
#pragma unroll
            for (int t = 0; t < KST; ++t) {
                bf16x8 af = *(const bf16x8*)(Ar + t * 32);
#pragma unroll
                for (int c = 0; c < NCT; ++c)
                    acc[r][c] = __builtin_amdgcn_mfma_f32_16x16x32_bf16(af, bf[c][t], acc[r][c],
                                                                       0, 0, 0);
            }
        }
    }

    // C/D layout: col = lane&15, row = quad*4 + j
#pragma unroll
    for (int r = 0; r < 4; ++r) {
        int row = n0 + r * 16 + quad * 4;
#pragma unroll
        for (int c = 0; c < NCT; ++c) {
            int col = c0 + c * 16 + lo;
#pragma unroll
            for (int j = 0; j < 4; ++j)
                if (row + j < N) C[(size_t)(row + j) * FOUT + col] = f2bf(acc[r][c][j]);
        }
    }

    // fused attention coefficients: per-row dot with a_src/a_dst over this
    // wave's columns, reduced across the 16 column-lanes, one atomic per row.
    float asv[NCT], adv[NCT];
#pragma unroll
    for (int c = 0; c < NCT; ++c) {
        int col = c0 + c * 16 + lo;
        asv[c] = a_src[col];
        adv[c] = a_dst[col];
    }
    const int h = c0 / (FOUT / H);
#pragma unroll
    for (int r = 0; r < 4; ++r) {
#pragma unroll
        for (int j = 0; j < 4; ++j) {
            float ps = 0.f, pd = 0.f;
#pragma unroll
            for (int c = 0; c < NCT; ++c) { ps += acc[r][c][j] * asv[c]; pd += acc[r][c][j] * adv[c]; }
#pragma unroll
            for (int off = 1; off <= 8; off <<= 1) {
                ps += __shfl_xor(ps, off, 64);
                pd += __shfl_xor(pd, off, 64);
            }
            int row = n0 + r * 16 + quad * 4 + j;
            if (lo == 0 && row < N) {
                atomicAdd(&es[row * H + h], ps);
                atomicAdd(&ed[row * H + h], pd);
            }
        }
    }
}

// ------------------------- GAT aggregation, H=2 (fused softmax) -----------

__global__ void gat_agg_h2(const unsigned short* __restrict__ Hpre,
                           const float* __restrict__ es, const float* __restrict__ ed,
                           float* __restrict__ w,
                           const int* __restrict__ rowptr, const int* __restrict__ csr_src,
                           const float* __restrict__ bias, unsigned short* __restrict__ out,
                           int N) {
    int wid = (blockIdx.x * blockDim.x + threadIdx.x) >> 6;
    int lane = threadIdx.x & 63;
    if (wid >= N) return;
    const int rs = rowptr[wid], re = rowptr[wid + 1];
    const int h = lane >> 5;
    const float edn = ed[wid * 2 + h];

    float z = 0.f;
    for (int i = rs + (lane & 31); i < re; i += 32) {
        int s = csr_src[i];
        float e = es[s * 2 + h] + edn;
        e = (e > 0.f) ? e : 0.2f * e;
        float ww = __expf(e);
        z += ww;
        w[i * 2 + h] = ww;
    }
#pragma unroll
    for (int off = 16; off >= 1; off >>= 1) z += __shfl_xor(z, off, 64);
    const float rz = 1.f / (z + 1e-16f);
    __threadfence_block();  // drain vmcnt: same-wave RAW on w

    float4 a0 = {0.f, 0.f, 0.f, 0.f}, a1 = {0.f, 0.f, 0.f, 0.f};
    float4 a2 = {0.f, 0.f, 0.f, 0.f}, a3 = {0.f, 0.f, 0.f, 0.f};
    int i = rs;
    for (; i + 4 <= re; i += 4) {
        int s0 = csr_src[i], s1 = csr_src[i + 1], s2 = csr_src[i + 2], s3 = csr_src[i + 3];
        float w0 = w[i * 2 + h], w1 = w[i * 2 + 2 + h];
        float w2 = w[i * 2 + 4 + h], w3 = w[i * 2 + 6 + h];
        ushort4 u0 = *(const ushort4*)(Hpre + (size_t)s0 * 256 + lane * 4);
        ushort4 u1 = *(const ushort4*)(Hpre + (size_t)s1 * 256 + lane * 4);
        ushort4 u2 = *(const ushort4*)(Hpre + (size_t)s2 * 256 + lane * 4);
        ushort4 u3 = *(const ushort4*)(Hpre + (size_t)s3 * 256 + lane * 4);
        a0.x += w0 * bf2f(u0.x); a0.y += w0 * bf2f(u0.y);
        a0.z += w0 * bf2f(u0.z); a0.w += w0 * bf2f(u0.w);
        a1.x += w1 * bf2f(u1.x); a1.y += w1 * bf2f(u1.y);
        a1.z += w1 * bf2f(u1.z); a1.w += w1 * bf2f(u1.w);
        a2.x += w2 * bf2f(u2.x); a2.y += w2 * bf2f(u2.y);
        a2.z += w2 * bf2f(u2.z); a2.w += w2 * bf2f(u2.w);
        a3.x += w3 * bf2f(u3.x); a3.y += w3 * bf2f(u3.y);
        a3.z += w3 * bf2f(u3.z); a3.w += w3 * bf2f(u3.w);
    }
    for (; i < re; ++i) {
        int s0 = csr_src[i];
        float w0 = w[i * 2 + h];
        ushort4 u0 = *(const ushort4*)(Hpre + (size_t)s0 * 256 + lane * 4);
        a0.x += w0 * bf2f(u0.x); a0.y += w0 * bf2f(u0.y);
        a0.z += w0 * bf2f(u0.z); a0.w += w0 * bf2f(u0.w);
    }
    float4 bv = ((const float4*)bias)[lane];
    float ox = (a0.x + a1.x + a2.x + a3.x) * rz + bv.x;
    float oy = (a0.y + a1.y + a2.y + a3.y) * rz + bv.y;
    float oz = (a0.z + a1.z + a2.z + a3.z) * rz + bv.z;
    float ow = (a0.w + a1.w + a2.w + a3.w) * rz + bv.w;
    ox = (ox > 0.f) ? ox : __expf(ox) - 1.f;
    oy = (oy > 0.f) ? oy : __expf(oy) - 1.f;
    oz = (oz > 0.f) ? oz : __expf(oz) - 1.f;
    ow = (ow > 0.f) ? ow : __expf(ow) - 1.f;
    ushort4 o;
    o.x = f2bf(ox); o.y = f2bf(oy); o.z = f2bf(oz); o.w = f2bf(ow);
    *(ushort4*)(out + (size_t)wid * 256 + lane * 4) = o;
}

// ------------------------- GAT aggregation, H=1 (fused softmax) -----------

__global__ void gat_agg_h1(const unsigned short* __restrict__ Hpre,
                           const float* __restrict__ es, const float* __restrict__ ed,
                           float* __restrict__ w,
                           const int* __restrict__ rowptr, const int* __restrict__ csr_src,
                           const float* __restrict__ bias, unsigned short* __restrict__ out,
                           int N) {
    int wid = (blockIdx.x * blockDim.x + threadIdx.x) >> 6;
    int lane = threadIdx.x & 63;
    if (wid >= N) return;
    const int rs = rowptr[wid], re = rowptr[wid + 1];
    const int half = lane >> 5, c = lane & 31;
    const float edn = ed[wid];

    float z = 0.f;
    for (int i = rs + lane; i < re; i += 64) {
        int s = csr_src[i];
        float e = es[s] + edn;
        e = (e > 0.f) ? e : 0.2f * e;
        float ww = __expf(e);
        z += ww;
        w[i] = ww;
    }
    z = wave_sum(z);
    const float rz = 1.f / (z + 1e-16f);
    __threadfence_block();  // drain vmcnt: same-wave RAW on w

    float4 a0 = {0.f, 0.f, 0.f, 0.f}, a1 = {0.f, 0.f, 0.f, 0.f};
    float4 a2 = {0.f, 0.f, 0.f, 0.f}, a3 = {0.f, 0.f, 0.f, 0.f};
    int i = rs + half;
    for (; i + 6 < re; i += 8) {
        int s0 = csr_src[i], s1 = csr_src[i + 2], s2 = csr_src[i + 4], s3 = csr_src[i + 6];
        float w0 = w[i], w1 = w[i + 2], w2 = w[i + 4], w3 = w[i + 6];
        ushort4 u0 = *(const ushort4*)(Hpre + (size_t)s0 * 128 + c * 4);
        ushort4 u1 = *(const ushort4*)(Hpre + (size_t)s1 * 128 + c * 4);
        ushort4 u2 = *(const ushort4*)(Hpre + (size_t)s2 * 128 + c * 4);
        ushort4 u3 = *(const ushort4*)(Hpre + (size_t)s3 * 128 + c * 4);
        a0.x += w0 * bf2f(u0.x); a0.y += w0 * bf2f(u0.y);
        a0.z += w0 * bf2f(u0.z); a0.w += w0 * bf2f(u0.w);
        a1.x += w1 * bf2f(u1.x); a1.y += w1 * bf2f(u1.y);
        a1.z += w1 * bf2f(u1.z); a1.w += w1 * bf2f(u1.w);
        a2.x += w2 * bf2f(u2.x); a2.y += w2 * bf2f(u2.y);
        a2.z += w2 * bf2f(u2.z); a2.w += w2 * bf2f(u2.w);
        a3.x += w3 * bf2f(u3.x); a3.y += w3 * bf2f(u3.y);
        a3.z += w3 * bf2f(u3.z); a3.w += w3 * bf2f(u3.w);
    }
    for (; i < re; i += 2) {
        int s0 = csr_src[i];
        float w0 = w[i];
        ushort4 u0 = *(const ushort4*)(Hpre + (size_t)s0 * 128 + c * 4);
        a0.x += w0 * bf2f(u0.x); a0.y += w0 * bf2f(u0.y);
        a0.z += w0 * bf2f(u0.z); a0.w += w0 * bf2f(u0.w);
    }
    float ox = a0.x + a1.x + a2.x + a3.x;
    float oy = a0.y + a1.y + a2.y + a3.y;
    float oz = a0.z + a1.z + a2.z + a3.z;
    float ow = a0.w + a1.w + a2.w + a3.w;
    ox += __shfl_xor(ox, 32, 64);
    oy += __shfl_xor(oy, 32, 64);
    oz += __shfl_xor(oz, 32, 64);
    ow += __shfl_xor(ow, 32, 64);
    if (lane < 32) {
        float4 bv = ((const float4*)bias)[c];
        ox = ox * rz + bv.x; oy = oy * rz + bv.y; oz = oz * rz + bv.z; ow = ow * rz + bv.w;
        ox = (ox > 0.f) ? ox : __expf(ox) - 1.f;
        oy = (oy > 0.f) ? oy : __expf(oy) - 1.f;
        oz = (oz > 0.f) ? oz : __expf(oz) - 1.f;
        ow = (ow > 0.f) ? ow : __expf(ow) - 1.f;
        ushort4 o;
        o.x = f2bf(ox); o.y = f2bf(oy); o.z = f2bf(oz); o.w = f2bf(ow);
        *(ushort4*)(out + (size_t)wid * 128 + c * 4) = o;
    }
}

// ------------------------- global mean pool (chunk-parallel) --------------

#define PCHUNK 256

__global__ __launch_bounds__(256) void pool_partial(const unsigned short* __restrict__ h2,
                                                    const int* __restrict__ batch,
                                                    float* __restrict__ xsum,
                                                    int* __restrict__ cnt, int N) {
    const int base = blockIdx.x * PCHUNK;
    const int rg = threadIdx.x >> 6;
    const int c2 = threadIdx.x & 63;
    float ax = 0.f, ay = 0.f;
    int gcur = -1, run = 0;
    for (int r = rg; r < PCHUNK; r += 4) {
        int i = base + r;
        if (i >= N) break;
        int g = batch[i];
        if (g != gcur) {
            if (gcur >= 0) {
                atomicAdd(&xsum[gcur * 128 + c2 * 2 + 0], ax);
                atomicAdd(&xsum[gcur * 128 + c2 * 2 + 1], ay);
                if (c2 == 0) atomicAdd(&cnt[gcur], run);
            }
            gcur = g; ax = 0.f; ay = 0.f; run = 0;
        }
        ushort2 u = *(const ushort2*)(h2 + (size_t)i * 128 + c2 * 2);
        ax += bf2f(u.x); ay += bf2f(u.y);
        run += 1;
    }
    if (gcur >= 0) {
        atomicAdd(&xsum[gcur * 128 + c2 * 2 + 0], ax);
        atomicAdd(&xsum[gcur * 128 + c2 * 2 + 1], ay);
        if (c2 == 0) atomicAdd(&cnt[gcur], run);
    }
}

// ------------------------- policy / value heads ---------------------------

__global__ void head_kernel(const float* __restrict__ xsum, const int* __restrict__ cnt,
                            const float* __restrict__ Wp, const float* __restrict__ bp,
                            const float* __restrict__ Wv, const float* __restrict__ bv,
                            float* __restrict__ out) {
    int g = blockIdx.x, t = threadIdx.x;  // 64 threads
    __shared__ float p[128];
    float inv = 1.f / fmaxf((float)cnt[g], 1.f);
    p[t] = xsum[g * 128 + t] * inv;
    p[t + 64] = xsum[g * 128 + t + 64] * inv;
    __syncthreads();
    if (t < 32) {
        float acc = bp[t];
        for (int k = 0; k < 128; ++k) acc += p[k] * Wp[k * 32 + t];
        out[g * 32 + t] = acc;
    } else if (t == 32) {
        float acc = bv[0];
        for (int k = 0; k < 128; ++k) acc += p[k] * Wv[k];
        out[64 * 32 + g] = acc;
    }
}

// ---------------------------------------------------------------------------

extern "C" void kernel_launch(void* const* d_in, const int* in_sizes, int n_in,
                              void* d_out, int out_size, void* d_ws, size_t ws_size,
                              hipStream_t stream) {
    const float* x      = (const float*)d_in[0];
    const int*   ei     = (const int*)d_in[1];
    const int*   batch  = (const int*)d_in[2];
    const float* W1     = (const float*)d_in[3];
    const float* a_src1 = (const float*)d_in[4];
    const float* a_dst1 = (const float*)d_in[5];
    const float* b1     = (const float*)d_in[6];
    const float* W2     = (const float*)d_in[7];
    const float* a_src2 = (const float*)d_in[8];
    const float* a_dst2 = (const float*)d_in[9];
    const float* b2     = (const float*)d_in[10];
    const float* Wp     = (const float*)d_in[11];
    const float* bp     = (const float*)d_in[12];
    const float* Wv     = (const float*)d_in[13];
    const float* bv     = (const float*)d_in[14];

    const int N  = in_sizes[0] / 128;
    const int E  = in_sizes[1] / 2;
    const int ET = E + N;
    const int TILES = (N + 1023) / 1024;
    const int NPAD = ((N + 63) / 64) * 64;
    const int NBLK = NPAD / 64;
    const int PBLK = (N + PCHUNK - 1) / PCHUNK;

    char* ws = (char*)d_ws;
    size_t off = 0;
    auto alloc = [&](size_t bytes) -> void* {
        void* p = ws + off;
        off = (off + bytes + 255) & ~(size_t)255;
        return p;
    };
    unsigned short* h1pre = (unsigned short*)alloc((size_t)NPAD * 256 * 2);  // reused as h2pre
    unsigned short* h1bf  = (unsigned short*)alloc((size_t)NPAD * 256 * 2);
    unsigned short* h2bf  = (unsigned short*)alloc((size_t)N * 128 * 2);
    unsigned short* w1sw  = (unsigned short*)alloc((size_t)128 * 256 * 2);
    unsigned short* w2sw  = (unsigned short*)alloc((size_t)256 * 128 * 2);
    float* wbuf   = (float*)alloc((size_t)ET * 2 * 4);
    // contiguous zero region: deg | es1 | ed1 | es2 | ed2 | xsum | cnt
    const int ZINTS = 7 * N + 64 * 128 + 64;
    int*   zbase  = (int*)alloc(((size_t)ZINTS + 4) * 4);
    int*   deg    = zbase;
    float* es1    = (float*)(zbase + N);
    float* ed1    = es1 + 2 * N;
    float* es2    = ed1 + 2 * N;
    float* ed2    = es2 + N;
    float* xsum   = ed2 + N;
    int*   cnt    = (int*)(xsum + 64 * 128);
    int*   rowptr = (int*)alloc((size_t)(N + 1) * 4);
    int*   cursor = (int*)alloc((size_t)N * 4);
    int*   csrsrc = (int*)alloc((size_t)ET * 4);
    int*   tsum   = (int*)alloc(64 * 4);
    unsigned short* h2pre = h1pre;  // h1pre dead after layer-1 agg

    // --- zero everything at once (ws is poisoned every call) ---
    zero4_kernel<<<((ZINTS + 3) / 4 + 255) / 256, 256, 0, stream>>>(zbase, (ZINTS + 3) / 4);

    // --- CSR build ---
    degree_kernel<<<(ET + 255) / 256, 256, 0, stream>>>(ei, deg, E, N);
    scan_tiles<<<TILES, 256, 0, stream>>>(deg, tsum, N);
    scan_add<<<TILES, 256, 0, stream>>>(deg, tsum, rowptr, cursor, N, TILES);
    scatter_kernel<<<(ET + 255) / 256, 256, 0, stream>>>(ei, cursor, csrsrc, E, N);

    // --- weight swizzles (one launch) ---
    swizzle_both<<<32, 256, 0, stream>>>(W1, W2, w1sw, w2sw);

    // --- layer 1: heads=2 (A = fp32 x, cast in-reg; es1/ed1 fused) ---
    gemm_mfma<128, 256, 2, true><<<NBLK, 256, 0, stream>>>(x, w1sw, a_src1, a_dst1,
                                                           es1, ed1, h1pre, N);
    gat_agg_h2<<<(N + 3) / 4, 256, 0, stream>>>(h1pre, es1, ed1, wbuf, rowptr, csrsrc, b1,
                                                h1bf, N);

    // --- layer 2: heads=1 (es2/ed2 fused) ---
    gemm_mfma<256, 128, 1, false><<<NBLK, 256, 0, stream>>>(h1bf, w2sw, a_src2, a_dst2,
                                                            es2, ed2, h2pre, N);
    gat_agg_h1<<<(N + 3) / 4, 256, 0, stream>>>(h2pre, es2, ed2, wbuf, rowptr, csrsrc, b2,
                                                h2bf, N);

    // --- pool + heads ---
    pool_partial<<<PBLK, 256, 0, stream>>>(h2bf, batch, xsum, cnt, N);
    head_kernel<<<64, 64, 0, stream>>>(xsum, cnt, Wp, bp, Wv, bv, (float*)d_out);
}